// Round 1
// baseline (7049.007 us; speedup 1.0000x reference)
//
#include <hip/hip_runtime.h>
#include <hip/hip_bf16.h>
#include <math.h>

#define HD 256     // hidden width
#define GB 128     // graphs in batch

// ---------- small utility kernels ----------
__global__ void k_fill(float* __restrict__ p, int n, float v) {
  int i = blockIdx.x * blockDim.x + threadIdx.x;
  if (i < n) p[i] = v;
}

__global__ void k_count_deg(const int* __restrict__ dst, float* __restrict__ deg, int e) {
  int i = blockIdx.x * blockDim.x + threadIdx.x;
  if (i < e) atomicAdd(&deg[dst[i]], 1.0f);
}

__global__ void k_rsqrt_inplace(float* __restrict__ p, int n) {
  int i = blockIdx.x * blockDim.x + threadIdx.x;
  if (i < n) p[i] = rsqrtf(p[i]);   // deg >= 1 (self-loop) so always valid
}

__global__ void k_relu(float* __restrict__ p, int n) {
  int i = blockIdx.x * blockDim.x + threadIdx.x;
  if (i < n) p[i] = fmaxf(p[i], 0.0f);
}

// ---------- fp32 tiled GEMM: C[M,256] = A[M,K] @ W[K,256] ----------
// BM=BN=64, BK=16, 256 threads, 4x4 per thread.
__global__ __launch_bounds__(256) void k_gemm(const float* __restrict__ A,
                                              const float* __restrict__ W,
                                              float* __restrict__ C,
                                              int M, int K) {
  __shared__ float As[16][68];   // [k][m], padded
  __shared__ float Ws[16][68];   // [k][n], padded
  const int bm = blockIdx.x * 64;
  const int bn = blockIdx.y * 64;
  const int tid = threadIdx.x;
  const int tx = tid & 15;       // col group
  const int ty = tid >> 4;       // row group (0..15)
  float acc[4][4] = {};

  for (int k0 = 0; k0 < K; k0 += 16) {
    { // A tile: 64 rows x 16 k
      int r  = tid >> 2;
      int c4 = (tid & 3) * 4;
      int row = bm + r;
      float4 v = make_float4(0.f, 0.f, 0.f, 0.f);
      if (row < M) v = *reinterpret_cast<const float4*>(&A[(size_t)row * K + k0 + c4]);
      As[c4 + 0][r] = v.x; As[c4 + 1][r] = v.y; As[c4 + 2][r] = v.z; As[c4 + 3][r] = v.w;
    }
    { // W tile: 16 k x 64 cols
      int r  = tid >> 4;
      int c4 = (tid & 15) * 4;
      float4 v = *reinterpret_cast<const float4*>(&W[(size_t)(k0 + r) * HD + bn + c4]);
      Ws[r][c4 + 0] = v.x; Ws[r][c4 + 1] = v.y; Ws[r][c4 + 2] = v.z; Ws[r][c4 + 3] = v.w;
    }
    __syncthreads();
#pragma unroll
    for (int kk = 0; kk < 16; ++kk) {
      float a[4], w[4];
#pragma unroll
      for (int i = 0; i < 4; ++i) a[i] = As[kk][ty * 4 + i];
#pragma unroll
      for (int j = 0; j < 4; ++j) w[j] = Ws[kk][tx * 4 + j];
#pragma unroll
      for (int i = 0; i < 4; ++i)
#pragma unroll
        for (int j = 0; j < 4; ++j)
          acc[i][j] = fmaf(a[i], w[j], acc[i][j]);
    }
    __syncthreads();
  }
#pragma unroll
  for (int i = 0; i < 4; ++i) {
    int row = bm + ty * 4 + i;
    if (row < M) {
      float4 v = make_float4(acc[i][0], acc[i][1], acc[i][2], acc[i][3]);
      *reinterpret_cast<float4*>(&C[(size_t)row * HD + bn + tx * 4]) = v;
    }
  }
}

// ---------- out[i,:] = b[:] + xw[i,:] * dinv[i]^2  (self-loop + bias) ----------
__global__ void k_init_out(const float4* __restrict__ xw, const float* __restrict__ dinv,
                           const float4* __restrict__ b, float4* __restrict__ out, int n) {
  int i = blockIdx.x * blockDim.x + threadIdx.x;
  if (i >= n * 64) return;                 // 64 float4 per row
  int row = i >> 6;
  int f4  = i & 63;
  float di = dinv[row];
  float c  = di * di;
  float4 x = xw[i];
  float4 bb = b[f4];
  out[i] = make_float4(bb.x + x.x * c, bb.y + x.y * c, bb.z + x.z * c, bb.w + x.w * c);
}

// ---------- edge scatter: out[dst,:] += xw[src,:] * dinv[src]*dinv[dst] ----------
// one wave (64 lanes) per edge, 4 floats per lane
__global__ __launch_bounds__(256) void k_scatter(const int* __restrict__ src,
                                                 const int* __restrict__ dst,
                                                 const float* __restrict__ dinv,
                                                 const float* __restrict__ xw,
                                                 float* __restrict__ out, int e) {
  int wave = (blockIdx.x * blockDim.x + threadIdx.x) >> 6;
  int lane = threadIdx.x & 63;
  if (wave >= e) return;
  int s = src[wave], d = dst[wave];
  float coef = dinv[s] * dinv[d];
  float4 v = reinterpret_cast<const float4*>(&xw[(size_t)s * HD])[lane];
  float* od = &out[(size_t)d * HD + lane * 4];
  atomicAdd(&od[0], v.x * coef);
  atomicAdd(&od[1], v.y * coef);
  atomicAdd(&od[2], v.z * coef);
  atomicAdd(&od[3], v.w * coef);
}

// ---------- global add pool ----------
__global__ __launch_bounds__(256) void k_pool(const float* __restrict__ h,
                                              const int* __restrict__ batch,
                                              float* __restrict__ scores, int n, int col_off) {
  int wave = (blockIdx.x * blockDim.x + threadIdx.x) >> 6;
  int lane = threadIdx.x & 63;
  if (wave >= n) return;
  int bb = batch[wave];
  float4 v = reinterpret_cast<const float4*>(&h[(size_t)wave * HD])[lane];
  float* srow = &scores[(size_t)bb * 512 + col_off + lane * 4];
  atomicAdd(&srow[0], v.x);
  atomicAdd(&srow[1], v.y);
  atomicAdd(&srow[2], v.z);
  atomicAdd(&srow[3], v.w);
}

// ---------- small dense MLP layer: out[r,c] = relu(in[r,:] . w[:,c] + bias[c]) ----------
__global__ void k_mlp_layer(const float* __restrict__ in, const float* __restrict__ w,
                            const float* __restrict__ bias, float* __restrict__ out,
                            int K, int C) {
  extern __shared__ float srow[];
  int r = blockIdx.x;
  for (int k = threadIdx.x; k < K; k += blockDim.x) srow[k] = in[(size_t)r * K + k];
  __syncthreads();
  int c = threadIdx.x;
  if (c < C) {
    float acc = bias[c];
    for (int k = 0; k < K; ++k) acc = fmaf(srow[k], w[(size_t)k * C + c], acc);
    out[(size_t)r * C + c] = fmaxf(acc, 0.f);
  }
}

// ---------- final layer + sigmoid ----------
__global__ void k_final(const float* __restrict__ h2, const float* __restrict__ lw2,
                        const float* __restrict__ lb2, float* __restrict__ out) {
  int r = threadIdx.x;   // 128 rows
  if (r < GB) {
    float acc = lb2[0];
    for (int k = 0; k < 128; ++k) acc = fmaf(h2[(size_t)r * 128 + k], lw2[k], acc);
    out[r] = 1.f / (1.f + expf(-acc));
  }
}

extern "C" void kernel_launch(void* const* d_in, const int* in_sizes, int n_in,
                              void* d_out, int out_size, void* d_ws, size_t ws_size,
                              hipStream_t stream) {
  const float* x[2]     = {(const float*)d_in[0], (const float*)d_in[1]};
  const int*   ei[2]    = {(const int*)d_in[2], (const int*)d_in[3]};
  const int*   batch[2] = {(const int*)d_in[4], (const int*)d_in[5]};
  const float* W[3] = {(const float*)d_in[6], (const float*)d_in[8], (const float*)d_in[10]};
  const float* b[3] = {(const float*)d_in[7], (const float*)d_in[9], (const float*)d_in[11]};
  const float* lw0 = (const float*)d_in[12]; const float* lb0 = (const float*)d_in[13];
  const float* lw1 = (const float*)d_in[14]; const float* lb1 = (const float*)d_in[15];
  const float* lw2 = (const float*)d_in[16]; const float* lb2 = (const float*)d_in[17];
  float* out = (float*)d_out;

  const int N = in_sizes[0] / 128;   // 20000
  const int E = in_sizes[2] / 2;     // 320000

  float* ws     = (float*)d_ws;
  float* buf0   = ws;                          // N*256  (XW)
  float* buf1   = buf0 + (size_t)N * HD;       // N*256  (aggregated)
  float* dinv   = buf1 + (size_t)N * HD;       // N
  float* scores = dinv + N;                    // 128*512
  float* m1     = scores + (size_t)GB * 512;   // 128*256
  float* m2     = m1 + (size_t)GB * HD;        // 128*128

  k_fill<<<(GB * 512 + 255) / 256, 256, 0, stream>>>(scores, GB * 512, 0.f);

  for (int g = 0; g < 2; ++g) {
    const int* srcp = ei[g];
    const int* dstp = ei[g] + E;

    // degrees (self-loop counted) -> dinv
    k_fill<<<(N + 255) / 256, 256, 0, stream>>>(dinv, N, 1.f);
    k_count_deg<<<(E + 255) / 256, 256, 0, stream>>>(dstp, dinv, E);
    k_rsqrt_inplace<<<(N + 255) / 256, 256, 0, stream>>>(dinv, N);

    const float* cur = x[g];
    int K = 128;
    for (int l = 0; l < 3; ++l) {
      dim3 grid((N + 63) / 64, HD / 64);
      k_gemm<<<grid, 256, 0, stream>>>(cur, W[l], buf0, N, K);
      k_init_out<<<(N * 64 + 255) / 256, 256, 0, stream>>>(
          (const float4*)buf0, dinv, (const float4*)b[l], (float4*)buf1, N);
      k_scatter<<<(E + 3) / 4, 256, 0, stream>>>(srcp, dstp, dinv, buf0, buf1, E);
      k_relu<<<(N * HD + 255) / 256, 256, 0, stream>>>(buf1, N * HD);
      cur = buf1;
      K = HD;
    }
    k_pool<<<(N + 3) / 4, 256, 0, stream>>>(buf1, batch[g], scores, N, g * HD);
  }

  k_mlp_layer<<<GB, 256, 512 * sizeof(float), stream>>>(scores, lw0, lb0, m1, 512, 256);
  k_mlp_layer<<<GB, 128, 256 * sizeof(float), stream>>>(m1, lw1, lb1, m2, 256, 128);
  k_final<<<1, GB, 0, stream>>>(m2, lw2, lb2, out);
}

// Round 2
// 801.702 us; speedup vs baseline: 8.7926x; 8.7926x over previous
//
#include <hip/hip_runtime.h>
#include <hip/hip_bf16.h>
#include <math.h>

#define HD 256     // hidden width
#define GB 128     // graphs in batch

// ---------- utility ----------
__global__ void k_fill_i(int* __restrict__ p, int n, int v) {
  int i = blockIdx.x * blockDim.x + threadIdx.x;
  if (i < n) p[i] = v;
}

__global__ void k_deg_int(const int* __restrict__ dst, int* __restrict__ deg, int e) {
  int i = blockIdx.x * blockDim.x + threadIdx.x;
  if (i < e) atomicAdd(&deg[dst[i]], 1);
}

// single-block exclusive scan of deg -> row_ptr; also dinv = rsqrt(deg+1)
__global__ __launch_bounds__(1024) void k_scan(const int* __restrict__ deg,
                                               int* __restrict__ row_ptr,
                                               float* __restrict__ dinv,
                                               int n, int e_total) {
  __shared__ int part[1024];
  int t = threadIdx.x;
  int chunk = (n + 1023) >> 10;
  int lo = t * chunk;
  int hi = min(lo + chunk, n);
  int s = 0;
  for (int i = lo; i < hi; ++i) s += deg[i];
  part[t] = s;
  __syncthreads();
  for (int off = 1; off < 1024; off <<= 1) {
    int v = (t >= off) ? part[t - off] : 0;
    __syncthreads();
    part[t] += v;
    __syncthreads();
  }
  int run = (t > 0) ? part[t - 1] : 0;
  for (int i = lo; i < hi; ++i) {
    row_ptr[i] = run;
    run += deg[i];
    dinv[i] = rsqrtf((float)(deg[i] + 1));
  }
  if (t == 1023) row_ptr[n] = e_total;
}

// place edges into CSR (by destination)
__global__ void k_build(const int* __restrict__ src, const int* __restrict__ dst,
                        const float* __restrict__ dinv, const int* __restrict__ row_ptr,
                        int* __restrict__ cursor, int* __restrict__ csr_src,
                        float* __restrict__ csr_w, int e) {
  int i = blockIdx.x * blockDim.x + threadIdx.x;
  if (i >= e) return;
  int d = dst[i], s = src[i];
  int pos = atomicAdd(&cursor[d], 1);
  int idx = row_ptr[d] + pos;
  csr_src[idx] = s;
  csr_w[idx] = dinv[s] * dinv[d];
}

// ---------- fp32 tiled GEMM: C[M,256] = A[M,K] @ W[K,256] ----------
__global__ __launch_bounds__(256) void k_gemm(const float* __restrict__ A,
                                              const float* __restrict__ W,
                                              float* __restrict__ C,
                                              int M, int K) {
  __shared__ float As[16][68];
  __shared__ float Ws[16][68];
  const int bm = blockIdx.x * 64;
  const int bn = blockIdx.y * 64;
  const int tid = threadIdx.x;
  const int tx = tid & 15;
  const int ty = tid >> 4;
  float acc[4][4] = {};

  for (int k0 = 0; k0 < K; k0 += 16) {
    {
      int r  = tid >> 2;
      int c4 = (tid & 3) * 4;
      int row = bm + r;
      float4 v = make_float4(0.f, 0.f, 0.f, 0.f);
      if (row < M) v = *reinterpret_cast<const float4*>(&A[(size_t)row * K + k0 + c4]);
      As[c4 + 0][r] = v.x; As[c4 + 1][r] = v.y; As[c4 + 2][r] = v.z; As[c4 + 3][r] = v.w;
    }
    {
      int r  = tid >> 4;
      int c4 = (tid & 15) * 4;
      float4 v = *reinterpret_cast<const float4*>(&W[(size_t)(k0 + r) * HD + bn + c4]);
      Ws[r][c4 + 0] = v.x; Ws[r][c4 + 1] = v.y; Ws[r][c4 + 2] = v.z; Ws[r][c4 + 3] = v.w;
    }
    __syncthreads();
#pragma unroll
    for (int kk = 0; kk < 16; ++kk) {
      float a[4], w[4];
#pragma unroll
      for (int i = 0; i < 4; ++i) a[i] = As[kk][ty * 4 + i];
#pragma unroll
      for (int j = 0; j < 4; ++j) w[j] = Ws[kk][tx * 4 + j];
#pragma unroll
      for (int i = 0; i < 4; ++i)
#pragma unroll
        for (int j = 0; j < 4; ++j)
          acc[i][j] = fmaf(a[i], w[j], acc[i][j]);
    }
    __syncthreads();
  }
#pragma unroll
  for (int i = 0; i < 4; ++i) {
    int row = bm + ty * 4 + i;
    if (row < M) {
      float4 v = make_float4(acc[i][0], acc[i][1], acc[i][2], acc[i][3]);
      *reinterpret_cast<float4*>(&C[(size_t)row * HD + bn + tx * 4]) = v;
    }
  }
}

// ---------- fused gather: out[d,:] = relu(b + dinv[d]^2*xw[d,:] + sum_e w_e*xw[s_e,:]) ----------
// one 64-lane wave per node, float4 per lane
__global__ __launch_bounds__(256) void k_gather(const float* __restrict__ xw,
                                                const int* __restrict__ row_ptr,
                                                const int* __restrict__ csr_src,
                                                const float* __restrict__ csr_w,
                                                const float* __restrict__ dinv,
                                                const float4* __restrict__ bias,
                                                float* __restrict__ out, int n) {
  int node = (blockIdx.x * blockDim.x + threadIdx.x) >> 6;
  int lane = threadIdx.x & 63;
  if (node >= n) return;
  float di = dinv[node];
  float c = di * di;
  float4 x = reinterpret_cast<const float4*>(&xw[(size_t)node * HD])[lane];
  float4 bb = bias[lane];
  float4 acc = make_float4(bb.x + c * x.x, bb.y + c * x.y, bb.z + c * x.z, bb.w + c * x.w);
  int beg = row_ptr[node], end = row_ptr[node + 1];
  for (int e = beg; e < end; ++e) {
    int s = csr_src[e];
    float w = csr_w[e];
    float4 v = reinterpret_cast<const float4*>(&xw[(size_t)s * HD])[lane];
    acc.x = fmaf(w, v.x, acc.x);
    acc.y = fmaf(w, v.y, acc.y);
    acc.z = fmaf(w, v.z, acc.z);
    acc.w = fmaf(w, v.w, acc.w);
  }
  float4 r = make_float4(fmaxf(acc.x, 0.f), fmaxf(acc.y, 0.f),
                         fmaxf(acc.z, 0.f), fmaxf(acc.w, 0.f));
  reinterpret_cast<float4*>(&out[(size_t)node * HD])[lane] = r;
}

// ---------- segmented pool (batch sorted): scores[g, col_off + c] = sum over nodes of graph g ----------
__global__ __launch_bounds__(256) void k_pool2(const float* __restrict__ h,
                                               const int* __restrict__ batch,
                                               float* __restrict__ scores,
                                               int n, int col_off) {
  int g = blockIdx.x;
  int c = threadIdx.x;
  int lo = 0, hi = n;
  while (lo < hi) { int m = (lo + hi) >> 1; if (batch[m] < g) lo = m + 1; else hi = m; }
  int beg = lo;
  lo = 0; hi = n;
  while (lo < hi) { int m = (lo + hi) >> 1; if (batch[m] < g + 1) lo = m + 1; else hi = m; }
  int end = lo;
  float acc = 0.f;
  for (int i = beg; i < end; ++i) acc += h[(size_t)i * HD + c];
  scores[(size_t)g * 512 + col_off + c] = acc;
}

// ---------- small dense MLP layer ----------
__global__ void k_mlp_layer(const float* __restrict__ in, const float* __restrict__ w,
                            const float* __restrict__ bias, float* __restrict__ out,
                            int K, int C) {
  extern __shared__ float srow[];
  int r = blockIdx.x;
  for (int k = threadIdx.x; k < K; k += blockDim.x) srow[k] = in[(size_t)r * K + k];
  __syncthreads();
  int c = threadIdx.x;
  if (c < C) {
    float acc = bias[c];
    for (int k = 0; k < K; ++k) acc = fmaf(srow[k], w[(size_t)k * C + c], acc);
    out[(size_t)r * C + c] = fmaxf(acc, 0.f);
  }
}

__global__ void k_final(const float* __restrict__ h2, const float* __restrict__ lw2,
                        const float* __restrict__ lb2, float* __restrict__ out) {
  int r = threadIdx.x;
  if (r < GB) {
    float acc = lb2[0];
    for (int k = 0; k < 128; ++k) acc = fmaf(h2[(size_t)r * 128 + k], lw2[k], acc);
    out[r] = 1.f / (1.f + expf(-acc));
  }
}

extern "C" void kernel_launch(void* const* d_in, const int* in_sizes, int n_in,
                              void* d_out, int out_size, void* d_ws, size_t ws_size,
                              hipStream_t stream) {
  const float* x[2]     = {(const float*)d_in[0], (const float*)d_in[1]};
  const int*   ei[2]    = {(const int*)d_in[2], (const int*)d_in[3]};
  const int*   batch[2] = {(const int*)d_in[4], (const int*)d_in[5]};
  const float* W[3] = {(const float*)d_in[6], (const float*)d_in[8], (const float*)d_in[10]};
  const float* b[3] = {(const float*)d_in[7], (const float*)d_in[9], (const float*)d_in[11]};
  const float* lw0 = (const float*)d_in[12]; const float* lb0 = (const float*)d_in[13];
  const float* lw1 = (const float*)d_in[14]; const float* lb1 = (const float*)d_in[15];
  const float* lw2 = (const float*)d_in[16]; const float* lb2 = (const float*)d_in[17];
  float* out = (float*)d_out;

  const int N = in_sizes[0] / 128;   // 20000
  const int E = in_sizes[2] / 2;     // 320000

  float* ws     = (float*)d_ws;
  float* buf0   = ws;                          // N*256  (XW)
  float* buf1   = buf0 + (size_t)N * HD;       // N*256  (aggregated)
  float* dinv   = buf1 + (size_t)N * HD;       // N
  float* csr_w  = dinv + N;                    // E
  float* scores = csr_w + E;                   // 128*512
  float* m1     = scores + (size_t)GB * 512;   // 128*256
  float* m2     = m1 + (size_t)GB * HD;        // 128*128
  int*   deg    = (int*)(m2 + (size_t)GB * 128); // N
  int*   row_ptr= deg + N;                     // N+1
  int*   cursor = row_ptr + N + 1;             // N
  int*   csr_src= cursor + N;                  // E

  for (int g = 0; g < 2; ++g) {
    const int* srcp = ei[g];
    const int* dstp = ei[g] + E;

    // ---- build CSR (once per graph, reused by all 3 layers) ----
    k_fill_i<<<(N + 255) / 256, 256, 0, stream>>>(deg, N, 0);
    k_deg_int<<<(E + 255) / 256, 256, 0, stream>>>(dstp, deg, E);
    k_scan<<<1, 1024, 0, stream>>>(deg, row_ptr, dinv, N, E);
    k_fill_i<<<(N + 255) / 256, 256, 0, stream>>>(cursor, N, 0);
    k_build<<<(E + 255) / 256, 256, 0, stream>>>(srcp, dstp, dinv, row_ptr,
                                                 cursor, csr_src, csr_w, E);

    // ---- 3 GCN layers ----
    const float* cur = x[g];
    int K = 128;
    for (int l = 0; l < 3; ++l) {
      dim3 grid((N + 63) / 64, HD / 64);
      k_gemm<<<grid, 256, 0, stream>>>(cur, W[l], buf0, N, K);
      k_gather<<<(N + 3) / 4, 256, 0, stream>>>(buf0, row_ptr, csr_src, csr_w,
                                                dinv, (const float4*)b[l], buf1, N);
      cur = buf1;
      K = HD;
    }
    k_pool2<<<GB, 256, 0, stream>>>(buf1, batch[g], scores, N, g * HD);
  }

  k_mlp_layer<<<GB, 256, 512 * sizeof(float), stream>>>(scores, lw0, lb0, m1, 512, 256);
  k_mlp_layer<<<GB, 128, 256 * sizeof(float), stream>>>(m1, lw1, lb1, m2, 256, 128);
  k_final<<<1, GB, 0, stream>>>(m2, lw2, lb2, out);
}

// Round 3
// 713.487 us; speedup vs baseline: 9.8797x; 1.1236x over previous
//
#include <hip/hip_runtime.h>
#include <hip/hip_bf16.h>
#include <math.h>

#define HD 256     // hidden width
#define GB 128     // graphs in batch

// ---------- utility ----------
__global__ void k_fill(float* __restrict__ p, int n, float v) {
  int i = blockIdx.x * blockDim.x + threadIdx.x;
  if (i < n) p[i] = v;
}

__global__ void k_fill_i(int* __restrict__ p, int n, int v) {
  int i = blockIdx.x * blockDim.x + threadIdx.x;
  if (i < n) p[i] = v;
}

__global__ void k_deg_int(const int* __restrict__ dst, int* __restrict__ deg, int e) {
  int i = blockIdx.x * blockDim.x + threadIdx.x;
  if (i < e) atomicAdd(&deg[dst[i]], 1);
}

// single-block exclusive scan of deg -> row_ptr; also dinv = rsqrt(deg+1)
__global__ __launch_bounds__(1024) void k_scan(const int* __restrict__ deg,
                                               int* __restrict__ row_ptr,
                                               float* __restrict__ dinv,
                                               int n, int e_total) {
  __shared__ int part[1024];
  int t = threadIdx.x;
  int chunk = (n + 1023) >> 10;
  int lo = t * chunk;
  int hi = min(lo + chunk, n);
  int s = 0;
  for (int i = lo; i < hi; ++i) s += deg[i];
  part[t] = s;
  __syncthreads();
  for (int off = 1; off < 1024; off <<= 1) {
    int v = (t >= off) ? part[t - off] : 0;
    __syncthreads();
    part[t] += v;
    __syncthreads();
  }
  int run = (t > 0) ? part[t - 1] : 0;
  for (int i = lo; i < hi; ++i) {
    row_ptr[i] = run;
    run += deg[i];
    dinv[i] = rsqrtf((float)(deg[i] + 1));
  }
  if (t == 1023) row_ptr[n] = e_total;
}

// place edges into CSR (by destination)
__global__ void k_build(const int* __restrict__ src, const int* __restrict__ dst,
                        const float* __restrict__ dinv, const int* __restrict__ row_ptr,
                        int* __restrict__ cursor, int* __restrict__ csr_src,
                        float* __restrict__ csr_w, int e) {
  int i = blockIdx.x * blockDim.x + threadIdx.x;
  if (i >= e) return;
  int d = dst[i], s = src[i];
  int pos = atomicAdd(&cursor[d], 1);
  int idx = row_ptr[d] + pos;
  csr_src[idx] = s;
  csr_w[idx] = dinv[s] * dinv[d];
}

// ---------- fp32 tiled GEMM: C[M,256] = A[M,K] @ W[K,256] ----------
__global__ __launch_bounds__(256) void k_gemm(const float* __restrict__ A,
                                              const float* __restrict__ W,
                                              float* __restrict__ C,
                                              int M, int K) {
  __shared__ float As[16][68];
  __shared__ float Ws[16][68];
  const int bm = blockIdx.x * 64;
  const int bn = blockIdx.y * 64;
  const int tid = threadIdx.x;
  const int tx = tid & 15;
  const int ty = tid >> 4;
  float acc[4][4] = {};

  for (int k0 = 0; k0 < K; k0 += 16) {
    {
      int r  = tid >> 2;
      int c4 = (tid & 3) * 4;
      int row = bm + r;
      float4 v = make_float4(0.f, 0.f, 0.f, 0.f);
      if (row < M) v = *reinterpret_cast<const float4*>(&A[(size_t)row * K + k0 + c4]);
      As[c4 + 0][r] = v.x; As[c4 + 1][r] = v.y; As[c4 + 2][r] = v.z; As[c4 + 3][r] = v.w;
    }
    {
      int r  = tid >> 4;
      int c4 = (tid & 15) * 4;
      float4 v = *reinterpret_cast<const float4*>(&W[(size_t)(k0 + r) * HD + bn + c4]);
      Ws[r][c4 + 0] = v.x; Ws[r][c4 + 1] = v.y; Ws[r][c4 + 2] = v.z; Ws[r][c4 + 3] = v.w;
    }
    __syncthreads();
#pragma unroll
    for (int kk = 0; kk < 16; ++kk) {
      float a[4], w[4];
#pragma unroll
      for (int i = 0; i < 4; ++i) a[i] = As[kk][ty * 4 + i];
#pragma unroll
      for (int j = 0; j < 4; ++j) w[j] = Ws[kk][tx * 4 + j];
#pragma unroll
      for (int i = 0; i < 4; ++i)
#pragma unroll
        for (int j = 0; j < 4; ++j)
          acc[i][j] = fmaf(a[i], w[j], acc[i][j]);
    }
    __syncthreads();
  }
#pragma unroll
  for (int i = 0; i < 4; ++i) {
    int row = bm + ty * 4 + i;
    if (row < M) {
      float4 v = make_float4(acc[i][0], acc[i][1], acc[i][2], acc[i][3]);
      *reinterpret_cast<float4*>(&C[(size_t)row * HD + bn + tx * 4]) = v;
    }
  }
}

// ---------- fused gather: out[d,:] = relu(b + dinv[d]^2*xw[d,:] + sum_e w_e*xw[s_e,:]) ----------
__global__ __launch_bounds__(256) void k_gather(const float* __restrict__ xw,
                                                const int* __restrict__ row_ptr,
                                                const int* __restrict__ csr_src,
                                                const float* __restrict__ csr_w,
                                                const float* __restrict__ dinv,
                                                const float4* __restrict__ bias,
                                                float* __restrict__ out, int n) {
  int node = (blockIdx.x * blockDim.x + threadIdx.x) >> 6;
  int lane = threadIdx.x & 63;
  if (node >= n) return;
  float di = dinv[node];
  float c = di * di;
  float4 x = reinterpret_cast<const float4*>(&xw[(size_t)node * HD])[lane];
  float4 bb = bias[lane];
  float4 acc = make_float4(bb.x + c * x.x, bb.y + c * x.y, bb.z + c * x.z, bb.w + c * x.w);
  int beg = row_ptr[node], end = row_ptr[node + 1];
  for (int e = beg; e < end; ++e) {
    int s = csr_src[e];
    float w = csr_w[e];
    float4 v = reinterpret_cast<const float4*>(&xw[(size_t)s * HD])[lane];
    acc.x = fmaf(w, v.x, acc.x);
    acc.y = fmaf(w, v.y, acc.y);
    acc.z = fmaf(w, v.z, acc.z);
    acc.w = fmaf(w, v.w, acc.w);
  }
  float4 r = make_float4(fmaxf(acc.x, 0.f), fmaxf(acc.y, 0.f),
                         fmaxf(acc.z, 0.f), fmaxf(acc.w, 0.f));
  reinterpret_cast<float4*>(&out[(size_t)node * HD])[lane] = r;
}

// ---------- node-parallel pool: one wave per 32-node slice, run-length local acc ----------
__global__ __launch_bounds__(256) void k_pool3(const float* __restrict__ h,
                                               const int* __restrict__ batch,
                                               float* __restrict__ scores,
                                               int n, int col_off) {
  int wave = (blockIdx.x * blockDim.x + threadIdx.x) >> 6;
  int lane = threadIdx.x & 63;
  int beg = wave * 32;
  if (beg >= n) return;
  int end = min(beg + 32, n);
  float4 acc = make_float4(0.f, 0.f, 0.f, 0.f);
  int cur = batch[beg];
  for (int i = beg; i < end; ++i) {
    int b = batch[i];
    if (b != cur) {
      float* srow = &scores[(size_t)cur * 512 + col_off + lane * 4];
      atomicAdd(&srow[0], acc.x); atomicAdd(&srow[1], acc.y);
      atomicAdd(&srow[2], acc.z); atomicAdd(&srow[3], acc.w);
      acc = make_float4(0.f, 0.f, 0.f, 0.f);
      cur = b;
    }
    float4 v = reinterpret_cast<const float4*>(&h[(size_t)i * HD])[lane];
    acc.x += v.x; acc.y += v.y; acc.z += v.z; acc.w += v.w;
  }
  float* srow = &scores[(size_t)cur * 512 + col_off + lane * 4];
  atomicAdd(&srow[0], acc.x); atomicAdd(&srow[1], acc.y);
  atomicAdd(&srow[2], acc.z); atomicAdd(&srow[3], acc.w);
}

// ---------- fused MLP head: 512 -> 256 -> 128 -> 1 + sigmoid, one block per graph ----------
__global__ __launch_bounds__(256) void k_head(const float* __restrict__ scores,
                                              const float* __restrict__ lw0, const float* __restrict__ lb0,
                                              const float* __restrict__ lw1, const float* __restrict__ lb1,
                                              const float* __restrict__ lw2, const float* __restrict__ lb2,
                                              float* __restrict__ out) {
  __shared__ float s_in[512];
  __shared__ float s_h1[256];
  __shared__ float s_h2[128];
  __shared__ float red[4];
  const int r = blockIdx.x;
  const int t = threadIdx.x;
  s_in[t]       = scores[(size_t)r * 512 + t];
  s_in[t + 256] = scores[(size_t)r * 512 + t + 256];
  __syncthreads();
  float acc = lb0[t];
#pragma unroll 8
  for (int k = 0; k < 512; ++k) acc = fmaf(s_in[k], lw0[k * 256 + t], acc);
  s_h1[t] = fmaxf(acc, 0.f);
  __syncthreads();
  if (t < 128) {
    float a = lb1[t];
#pragma unroll 8
    for (int k = 0; k < 256; ++k) a = fmaf(s_h1[k], lw1[k * 128 + t], a);
    s_h2[t] = fmaxf(a, 0.f);
  }
  __syncthreads();
  float p = (t < 128) ? s_h2[t] * lw2[t] : 0.f;
#pragma unroll
  for (int off = 32; off; off >>= 1) p += __shfl_down(p, off);
  if ((t & 63) == 0) red[t >> 6] = p;
  __syncthreads();
  if (t == 0) {
    float z = red[0] + red[1] + red[2] + red[3] + lb2[0];
    out[r] = 1.f / (1.f + expf(-z));
  }
}

extern "C" void kernel_launch(void* const* d_in, const int* in_sizes, int n_in,
                              void* d_out, int out_size, void* d_ws, size_t ws_size,
                              hipStream_t stream) {
  const float* x[2]     = {(const float*)d_in[0], (const float*)d_in[1]};
  const int*   ei[2]    = {(const int*)d_in[2], (const int*)d_in[3]};
  const int*   batch[2] = {(const int*)d_in[4], (const int*)d_in[5]};
  const float* W[3] = {(const float*)d_in[6], (const float*)d_in[8], (const float*)d_in[10]};
  const float* b[3] = {(const float*)d_in[7], (const float*)d_in[9], (const float*)d_in[11]};
  const float* lw0 = (const float*)d_in[12]; const float* lb0 = (const float*)d_in[13];
  const float* lw1 = (const float*)d_in[14]; const float* lb1 = (const float*)d_in[15];
  const float* lw2 = (const float*)d_in[16]; const float* lb2 = (const float*)d_in[17];
  float* out = (float*)d_out;

  const int N = in_sizes[0] / 128;   // 20000
  const int E = in_sizes[2] / 2;     // 320000

  float* ws     = (float*)d_ws;
  float* buf0   = ws;                          // N*256  (XW)
  float* buf1   = buf0 + (size_t)N * HD;       // N*256  (aggregated)
  float* dinv   = buf1 + (size_t)N * HD;       // N
  float* csr_w  = dinv + N;                    // E
  float* scores = csr_w + E;                   // 128*512
  int*   deg    = (int*)(scores + (size_t)GB * 512); // N
  int*   row_ptr= deg + N;                     // N+1
  int*   cursor = row_ptr + N + 1;             // N
  int*   csr_src= cursor + N;                  // E

  k_fill<<<(GB * 512 + 255) / 256, 256, 0, stream>>>(scores, GB * 512, 0.f);

  for (int g = 0; g < 2; ++g) {
    const int* srcp = ei[g];
    const int* dstp = ei[g] + E;

    // ---- build CSR (once per graph, reused by all 3 layers) ----
    k_fill_i<<<(N + 255) / 256, 256, 0, stream>>>(deg, N, 0);
    k_deg_int<<<(E + 255) / 256, 256, 0, stream>>>(dstp, deg, E);
    k_scan<<<1, 1024, 0, stream>>>(deg, row_ptr, dinv, N, E);
    k_fill_i<<<(N + 255) / 256, 256, 0, stream>>>(cursor, N, 0);
    k_build<<<(E + 255) / 256, 256, 0, stream>>>(srcp, dstp, dinv, row_ptr,
                                                 cursor, csr_src, csr_w, E);

    // ---- 3 GCN layers ----
    const float* cur = x[g];
    int K = 128;
    for (int l = 0; l < 3; ++l) {
      dim3 grid((N + 63) / 64, HD / 64);
      k_gemm<<<grid, 256, 0, stream>>>(cur, W[l], buf0, N, K);
      k_gather<<<(N + 3) / 4, 256, 0, stream>>>(buf0, row_ptr, csr_src, csr_w,
                                                dinv, (const float4*)b[l], buf1, N);
      cur = buf1;
      K = HD;
    }
    // pool: one wave per 32-node slice
    int waves = (N + 31) / 32;
    k_pool3<<<(waves + 3) / 4, 256, 0, stream>>>(buf1, batch[g], scores, N, g * HD);
  }

  k_head<<<GB, 256, 0, stream>>>(scores, lw0, lb0, lw1, lb1, lw2, lb2, out);
}

// Round 4
// 440.365 us; speedup vs baseline: 16.0072x; 1.6202x over previous
//
#include <hip/hip_runtime.h>
#include <hip/hip_bf16.h>
#include <math.h>

#define HD 256
#define GB 128

typedef __attribute__((ext_vector_type(8))) short bf16x8;
typedef __attribute__((ext_vector_type(4))) float f32x4;

__device__ __forceinline__ float bf2f(unsigned short u) {
  return __uint_as_float(((unsigned int)u) << 16);
}
__device__ __forceinline__ unsigned short f2bf(float f) {
  unsigned int u = __float_as_uint(f);
  unsigned int r = u + 0x7FFFu + ((u >> 16) & 1u);
  return (unsigned short)(r >> 16);
}

// ---------- utility ----------
__global__ void k_fill(float* __restrict__ p, int n, float v) {
  int i = blockIdx.x * blockDim.x + threadIdx.x;
  if (i < n) p[i] = v;
}
__global__ void k_fill_i(int* __restrict__ p, int n, int v) {
  int i = blockIdx.x * blockDim.x + threadIdx.x;
  if (i < n) p[i] = v;
}

// fp32 -> bf16 (vectorized 4/thread)
__global__ void k_cvt(const float4* __restrict__ in, ushort4* __restrict__ out, int n4) {
  int i = blockIdx.x * blockDim.x + threadIdx.x;
  if (i >= n4) return;
  float4 v = in[i];
  ushort4 o;
  o.x = f2bf(v.x); o.y = f2bf(v.y); o.z = f2bf(v.z); o.w = f2bf(v.w);
  out[i] = o;
}

// pack weights: Wt[(k>>3)*256 + c][j=k&7] = bf16(W[k][c])
__global__ void k_prep_w(const float* __restrict__ W, unsigned short* __restrict__ Wt, int K) {
  int i = blockIdx.x * blockDim.x + threadIdx.x;
  if (i >= K * HD) return;
  int k = i >> 8, c = i & 255;
  Wt[(((size_t)(k >> 3) * HD) + c) * 8 + (k & 7)] = f2bf(W[i]);
}

__global__ void k_deg(const int* __restrict__ dst, int* __restrict__ deg, int e, int off) {
  int i = blockIdx.x * blockDim.x + threadIdx.x;
  if (i < e) atomicAdd(&deg[dst[i] + off], 1);
}

// single-block exclusive scan of deg -> row_ptr; dinv = rsqrt(deg+1)
__global__ __launch_bounds__(1024) void k_scan(const int* __restrict__ deg,
                                               int* __restrict__ row_ptr,
                                               float* __restrict__ dinv,
                                               int n, int e_total) {
  __shared__ int part[1024];
  int t = threadIdx.x;
  int chunk = (n + 1023) >> 10;
  int lo = t * chunk;
  int hi = min(lo + chunk, n);
  int s = 0;
  for (int i = lo; i < hi; ++i) s += deg[i];
  part[t] = s;
  __syncthreads();
  for (int off = 1; off < 1024; off <<= 1) {
    int v = (t >= off) ? part[t - off] : 0;
    __syncthreads();
    part[t] += v;
    __syncthreads();
  }
  int run = (t > 0) ? part[t - 1] : 0;
  for (int i = lo; i < hi; ++i) {
    row_ptr[i] = run;
    run += deg[i];
    dinv[i] = rsqrtf((float)(deg[i] + 1));
  }
  if (t == 1023) row_ptr[n] = e_total;
}

__global__ void k_build(const int* __restrict__ src, const int* __restrict__ dst,
                        const float* __restrict__ dinv, const int* __restrict__ row_ptr,
                        int* __restrict__ cursor, int* __restrict__ csr_src,
                        float* __restrict__ csr_w, int e, int off) {
  int i = blockIdx.x * blockDim.x + threadIdx.x;
  if (i >= e) return;
  int d = dst[i] + off, s = src[i] + off;
  int pos = atomicAdd(&cursor[d], 1);
  int idx = row_ptr[d] + pos;
  csr_src[idx] = s;
  csr_w[idx] = dinv[s] * dinv[d];
}

// ---------- MFMA bf16 GEMM: C[M,256] = A[M,K] @ W  (Wt packed [K/8][256][8]) ----------
// grid (M/64, 2); 256 thr = 4 waves; wave w: rows bm+w*16..+16, cols bn..bn+128
__global__ __launch_bounds__(256) void k_gemm_bf(const unsigned short* __restrict__ A,
                                                 const unsigned short* __restrict__ Wt,
                                                 unsigned short* __restrict__ C,
                                                 int K) {
  const int w = threadIdx.x >> 6;
  const int lane = threadIdx.x & 63;
  const int bm = blockIdx.x * 64 + w * 16;
  const int bn = blockIdx.y * 128;
  const int row = bm + (lane & 15);
  const int kg0 = lane >> 4;                       // 0..3
  f32x4 acc[8];
#pragma unroll
  for (int i = 0; i < 8; ++i) acc[i] = (f32x4){0.f, 0.f, 0.f, 0.f};

  const unsigned short* arow = A + (size_t)row * K + kg0 * 8;
  for (int k0 = 0; k0 < K; k0 += 32) {
    bf16x8 a = *(const bf16x8*)(arow + k0);
    const unsigned short* bbase =
        Wt + (((size_t)((k0 >> 3) + kg0) * HD) + bn + (lane & 15)) * 8;
#pragma unroll
    for (int nt = 0; nt < 8; ++nt) {
      bf16x8 b = *(const bf16x8*)(bbase + (size_t)nt * 16 * 8);
      acc[nt] = __builtin_amdgcn_mfma_f32_16x16x32_bf16(a, b, acc[nt], 0, 0, 0);
    }
  }
  // C/D: col = lane&15, row = (lane>>4)*4 + r
  const int crow = bm + (lane >> 4) * 4;
  const int ccol = bn + (lane & 15);
#pragma unroll
  for (int nt = 0; nt < 8; ++nt)
#pragma unroll
    for (int r = 0; r < 4; ++r)
      C[(size_t)(crow + r) * HD + ccol + nt * 16] = f2bf(acc[nt][r]);
}

// ---------- fused gather (bf16 rows): out[d,:] = relu(b + dinv^2*xw[d] + sum w_e*xw[s_e]) ----------
__global__ __launch_bounds__(256) void k_gather_bf(const unsigned short* __restrict__ xw,
                                                   const int* __restrict__ row_ptr,
                                                   const int* __restrict__ csr_src,
                                                   const float* __restrict__ csr_w,
                                                   const float* __restrict__ dinv,
                                                   const float4* __restrict__ bias,
                                                   unsigned short* __restrict__ out, int n) {
  int node = (blockIdx.x * blockDim.x + threadIdx.x) >> 6;
  int lane = threadIdx.x & 63;
  if (node >= n) return;
  float di = dinv[node];
  float c = di * di;
  ushort4 xv = reinterpret_cast<const ushort4*>(xw + (size_t)node * HD)[lane];
  float4 bb = bias[lane];
  float ax = bb.x + c * bf2f(xv.x);
  float ay = bb.y + c * bf2f(xv.y);
  float az = bb.z + c * bf2f(xv.z);
  float aw = bb.w + c * bf2f(xv.w);
  float bx = 0.f, by = 0.f, bz = 0.f, bw = 0.f;
  int e = row_ptr[node], end = row_ptr[node + 1];
  for (; e + 2 <= end; e += 2) {
    int s0 = csr_src[e], s1 = csr_src[e + 1];
    float w0 = csr_w[e], w1 = csr_w[e + 1];
    ushort4 v0 = reinterpret_cast<const ushort4*>(xw + (size_t)s0 * HD)[lane];
    ushort4 v1 = reinterpret_cast<const ushort4*>(xw + (size_t)s1 * HD)[lane];
    ax = fmaf(w0, bf2f(v0.x), ax); ay = fmaf(w0, bf2f(v0.y), ay);
    az = fmaf(w0, bf2f(v0.z), az); aw = fmaf(w0, bf2f(v0.w), aw);
    bx = fmaf(w1, bf2f(v1.x), bx); by = fmaf(w1, bf2f(v1.y), by);
    bz = fmaf(w1, bf2f(v1.z), bz); bw = fmaf(w1, bf2f(v1.w), bw);
  }
  if (e < end) {
    int s0 = csr_src[e];
    float w0 = csr_w[e];
    ushort4 v0 = reinterpret_cast<const ushort4*>(xw + (size_t)s0 * HD)[lane];
    ax = fmaf(w0, bf2f(v0.x), ax); ay = fmaf(w0, bf2f(v0.y), ay);
    az = fmaf(w0, bf2f(v0.z), az); aw = fmaf(w0, bf2f(v0.w), aw);
  }
  ax += bx; ay += by; az += bz; aw += bw;
  ushort4 o;
  o.x = f2bf(fmaxf(ax, 0.f)); o.y = f2bf(fmaxf(ay, 0.f));
  o.z = f2bf(fmaxf(az, 0.f)); o.w = f2bf(fmaxf(aw, 0.f));
  reinterpret_cast<ushort4*>(out + (size_t)node * HD)[lane] = o;
}

// ---------- pool over merged node space: wave per 32-node slice ----------
__global__ __launch_bounds__(256) void k_pool4(const unsigned short* __restrict__ h,
                                               const int* __restrict__ batch1,
                                               const int* __restrict__ batch2,
                                               float* __restrict__ scores,
                                               int n, int n0) {
  int wave = (blockIdx.x * blockDim.x + threadIdx.x) >> 6;
  int lane = threadIdx.x & 63;
  int beg = wave * 32;
  if (beg >= n) return;
  int end = min(beg + 32, n);
  bool g1 = beg >= n0;                       // n0 % 32 == 0 -> slice never crosses
  const int* bat = g1 ? batch2 : batch1;
  int boff = g1 ? n0 : 0;
  int coff = g1 ? HD : 0;
  float ax = 0.f, ay = 0.f, az = 0.f, aw = 0.f;
  int cur = bat[beg - boff];
  for (int i = beg; i < end; ++i) {
    int b = bat[i - boff];
    if (b != cur) {
      float* srow = &scores[(size_t)cur * 512 + coff + lane * 4];
      atomicAdd(&srow[0], ax); atomicAdd(&srow[1], ay);
      atomicAdd(&srow[2], az); atomicAdd(&srow[3], aw);
      ax = ay = az = aw = 0.f;
      cur = b;
    }
    ushort4 v = reinterpret_cast<const ushort4*>(h + (size_t)i * HD)[lane];
    ax += bf2f(v.x); ay += bf2f(v.y); az += bf2f(v.z); aw += bf2f(v.w);
  }
  float* srow = &scores[(size_t)cur * 512 + coff + lane * 4];
  atomicAdd(&srow[0], ax); atomicAdd(&srow[1], ay);
  atomicAdd(&srow[2], az); atomicAdd(&srow[3], aw);
}

// ---------- fused MLP head ----------
__global__ __launch_bounds__(256) void k_head(const float* __restrict__ scores,
                                              const float* __restrict__ lw0, const float* __restrict__ lb0,
                                              const float* __restrict__ lw1, const float* __restrict__ lb1,
                                              const float* __restrict__ lw2, const float* __restrict__ lb2,
                                              float* __restrict__ out) {
  __shared__ float s_in[512];
  __shared__ float s_h1[256];
  __shared__ float s_h2[128];
  __shared__ float red[4];
  const int r = blockIdx.x;
  const int t = threadIdx.x;
  s_in[t]       = scores[(size_t)r * 512 + t];
  s_in[t + 256] = scores[(size_t)r * 512 + t + 256];
  __syncthreads();
  float acc = lb0[t];
#pragma unroll 8
  for (int k = 0; k < 512; ++k) acc = fmaf(s_in[k], lw0[k * 256 + t], acc);
  s_h1[t] = fmaxf(acc, 0.f);
  __syncthreads();
  if (t < 128) {
    float a = lb1[t];
#pragma unroll 8
    for (int k = 0; k < 256; ++k) a = fmaf(s_h1[k], lw1[k * 128 + t], a);
    s_h2[t] = fmaxf(a, 0.f);
  }
  __syncthreads();
  float p = (t < 128) ? s_h2[t] * lw2[t] : 0.f;
#pragma unroll
  for (int off = 32; off; off >>= 1) p += __shfl_down(p, off);
  if ((t & 63) == 0) red[t >> 6] = p;
  __syncthreads();
  if (t == 0) {
    float z = red[0] + red[1] + red[2] + red[3] + lb2[0];
    out[r] = 1.f / (1.f + expf(-z));
  }
}

extern "C" void kernel_launch(void* const* d_in, const int* in_sizes, int n_in,
                              void* d_out, int out_size, void* d_ws, size_t ws_size,
                              hipStream_t stream) {
  const float* x1 = (const float*)d_in[0];
  const float* x2 = (const float*)d_in[1];
  const int* ei1 = (const int*)d_in[2];
  const int* ei2 = (const int*)d_in[3];
  const int* batch1 = (const int*)d_in[4];
  const int* batch2 = (const int*)d_in[5];
  const float* W0 = (const float*)d_in[6];  const float* b0 = (const float*)d_in[7];
  const float* W1 = (const float*)d_in[8];  const float* b1 = (const float*)d_in[9];
  const float* W2 = (const float*)d_in[10]; const float* b2 = (const float*)d_in[11];
  const float* lw0 = (const float*)d_in[12]; const float* lb0 = (const float*)d_in[13];
  const float* lw1 = (const float*)d_in[14]; const float* lb1 = (const float*)d_in[15];
  const float* lw2 = (const float*)d_in[16]; const float* lb2 = (const float*)d_in[17];
  float* out = (float*)d_out;

  const int N = in_sizes[0] / 128;   // 20000
  const int E = in_sizes[2] / 2;     // 320000
  const int N2 = 2 * N, E2 = 2 * E;

  char* p = (char*)d_ws;
  unsigned short* x_bf = (unsigned short*)p; p += (size_t)N2 * 128 * 2;
  unsigned short* buf0 = (unsigned short*)p; p += (size_t)N2 * HD * 2;
  unsigned short* buf1 = (unsigned short*)p; p += (size_t)N2 * HD * 2;
  unsigned short* Wt0  = (unsigned short*)p; p += (size_t)128 * HD * 2;
  unsigned short* Wt1  = (unsigned short*)p; p += (size_t)HD * HD * 2;
  unsigned short* Wt2  = (unsigned short*)p; p += (size_t)HD * HD * 2;
  float* dinv   = (float*)p; p += (size_t)N2 * 4;
  float* csr_w  = (float*)p; p += (size_t)E2 * 4;
  float* scores = (float*)p; p += (size_t)GB * 512 * 4;
  int* deg     = (int*)p; p += (size_t)N2 * 4;
  int* row_ptr = (int*)p; p += (size_t)(N2 + 1) * 4;
  int* cursor  = (int*)p; p += (size_t)N2 * 4;
  int* csr_src = (int*)p; p += (size_t)E2 * 4;

  // weight packing + input conversion
  k_prep_w<<<(128 * HD + 255) / 256, 256, 0, stream>>>(W0, Wt0, 128);
  k_prep_w<<<(HD * HD + 255) / 256, 256, 0, stream>>>(W1, Wt1, HD);
  k_prep_w<<<(HD * HD + 255) / 256, 256, 0, stream>>>(W2, Wt2, HD);
  k_cvt<<<((N * 128 / 4) + 255) / 256, 256, 0, stream>>>(
      (const float4*)x1, (ushort4*)x_bf, N * 128 / 4);
  k_cvt<<<((N * 128 / 4) + 255) / 256, 256, 0, stream>>>(
      (const float4*)x2, (ushort4*)(x_bf + (size_t)N * 128), N * 128 / 4);
  k_fill<<<(GB * 512 + 255) / 256, 256, 0, stream>>>(scores, GB * 512, 0.f);

  // merged CSR
  k_fill_i<<<(N2 + 255) / 256, 256, 0, stream>>>(deg, N2, 0);
  k_deg<<<(E + 255) / 256, 256, 0, stream>>>(ei1 + E, deg, E, 0);
  k_deg<<<(E + 255) / 256, 256, 0, stream>>>(ei2 + E, deg, E, N);
  k_scan<<<1, 1024, 0, stream>>>(deg, row_ptr, dinv, N2, E2);
  k_fill_i<<<(N2 + 255) / 256, 256, 0, stream>>>(cursor, N2, 0);
  k_build<<<(E + 255) / 256, 256, 0, stream>>>(ei1, ei1 + E, dinv, row_ptr,
                                               cursor, csr_src, csr_w, E, 0);
  k_build<<<(E + 255) / 256, 256, 0, stream>>>(ei2, ei2 + E, dinv, row_ptr,
                                               cursor, csr_src, csr_w, E, N);

  // 3 GCN layers over the merged 40000-node problem
  dim3 ggrid(N2 / 64, 2);
  k_gemm_bf<<<ggrid, 256, 0, stream>>>(x_bf, Wt0, buf0, 128);
  k_gather_bf<<<(N2 + 3) / 4, 256, 0, stream>>>(buf0, row_ptr, csr_src, csr_w,
                                                dinv, (const float4*)b0, buf1, N2);
  k_gemm_bf<<<ggrid, 256, 0, stream>>>(buf1, Wt1, buf0, HD);
  k_gather_bf<<<(N2 + 3) / 4, 256, 0, stream>>>(buf0, row_ptr, csr_src, csr_w,
                                                dinv, (const float4*)b1, buf1, N2);
  k_gemm_bf<<<ggrid, 256, 0, stream>>>(buf1, Wt2, buf0, HD);
  k_gather_bf<<<(N2 + 3) / 4, 256, 0, stream>>>(buf0, row_ptr, csr_src, csr_w,
                                                dinv, (const float4*)b2, buf1, N2);

  int waves = N2 / 32;
  k_pool4<<<(waves + 3) / 4, 256, 0, stream>>>(buf1, batch1, batch2, scores, N2, N);
  k_head<<<GB, 256, 0, stream>>>(scores, lw0, lb0, lw1, lb1, lw2, lb2, out);
}

// Round 5
// 351.712 us; speedup vs baseline: 20.0420x; 1.2521x over previous
//
#include <hip/hip_runtime.h>
#include <hip/hip_bf16.h>
#include <math.h>

#define HD 256
#define GB 128

typedef __attribute__((ext_vector_type(8))) short bf16x8;
typedef __attribute__((ext_vector_type(4))) float f32x4;

__device__ __forceinline__ float bf2f(unsigned short u) {
  return __uint_as_float(((unsigned int)u) << 16);
}
__device__ __forceinline__ unsigned short f2bf(float f) {
  unsigned int u = __float_as_uint(f);
  unsigned int r = u + 0x7FFFu + ((u >> 16) & 1u);
  return (unsigned short)(r >> 16);
}

// ---------- utility ----------
__global__ void k_fill(float* __restrict__ p, int n, float v) {
  int i = blockIdx.x * blockDim.x + threadIdx.x;
  if (i < n) p[i] = v;
}
__global__ void k_fill_i(int* __restrict__ p, int n, int v) {
  int i = blockIdx.x * blockDim.x + threadIdx.x;
  if (i < n) p[i] = v;
}

// fp32 -> bf16 for both inputs in one grid
__global__ void k_cvt2(const float4* __restrict__ in1, const float4* __restrict__ in2,
                       ushort4* __restrict__ out, int n4) {   // n4 per input
  int i = blockIdx.x * blockDim.x + threadIdx.x;
  if (i >= 2 * n4) return;
  float4 v = (i < n4) ? in1[i] : in2[i - n4];
  ushort4 o;
  o.x = f2bf(v.x); o.y = f2bf(v.y); o.z = f2bf(v.z); o.w = f2bf(v.w);
  out[i] = o;
}

// pack weights: Wt[(k>>3)*256 + c][j=k&7] = bf16(W[k][c])
__global__ void k_prep_w(const float* __restrict__ W, unsigned short* __restrict__ Wt, int K) {
  int i = blockIdx.x * blockDim.x + threadIdx.x;
  if (i >= K * HD) return;
  int k = i >> 8, c = i & 255;
  Wt[(((size_t)(k >> 3) * HD) + c) * 8 + (k & 7)] = f2bf(W[i]);
}

// degrees for both graphs in one launch
__global__ void k_deg2(const int* __restrict__ dst1, const int* __restrict__ dst2,
                       int* __restrict__ deg, int e, int n0) {
  int i = blockIdx.x * blockDim.x + threadIdx.x;
  if (i >= 2 * e) return;
  int d = (i < e) ? dst1[i] : (dst2[i - e] + n0);
  atomicAdd(&deg[d], 1);
}

// ---------- 3-phase scan ----------
__global__ __launch_bounds__(256) void k_scan_a(const int* __restrict__ deg,
                                                int* __restrict__ partial, int n) {
  __shared__ int sh[256];
  int i = blockIdx.x * 256 + threadIdx.x;
  int v = (i < n) ? deg[i] : 0;
  sh[threadIdx.x] = v;
  __syncthreads();
#pragma unroll
  for (int off = 128; off; off >>= 1) {
    if (threadIdx.x < off) sh[threadIdx.x] += sh[threadIdx.x + off];
    __syncthreads();
  }
  if (threadIdx.x == 0) partial[blockIdx.x] = sh[0];
}

__global__ __launch_bounds__(256) void k_scan_b(int* __restrict__ partial, int nb,
                                                int* __restrict__ row_ptr, int n, int e_total) {
  __shared__ int sh[256];
  int t = threadIdx.x;
  int v = (t < nb) ? partial[t] : 0;
  sh[t] = v;
  __syncthreads();
#pragma unroll
  for (int off = 1; off < 256; off <<= 1) {
    int u = (t >= off) ? sh[t - off] : 0;
    __syncthreads();
    sh[t] += u;
    __syncthreads();
  }
  if (t < nb) partial[t] = sh[t] - v;   // exclusive
  if (t == 0) row_ptr[n] = e_total;
}

__global__ __launch_bounds__(256) void k_scan_c(const int* __restrict__ deg,
                                                const int* __restrict__ partial,
                                                int* __restrict__ row_ptr,
                                                float* __restrict__ dinv, int n) {
  __shared__ int sh[256];
  int i = blockIdx.x * 256 + threadIdx.x;
  int t = threadIdx.x;
  int v = (i < n) ? deg[i] : 0;
  sh[t] = v;
  __syncthreads();
#pragma unroll
  for (int off = 1; off < 256; off <<= 1) {
    int u = (t >= off) ? sh[t - off] : 0;
    __syncthreads();
    sh[t] += u;
    __syncthreads();
  }
  if (i < n) {
    row_ptr[i] = sh[t] - v + partial[blockIdx.x];
    dinv[i] = rsqrtf((float)(v + 1));
  }
}

// CSR build for both graphs in one launch
__global__ void k_build2(const int* __restrict__ ei1, const int* __restrict__ ei2,
                         const float* __restrict__ dinv, const int* __restrict__ row_ptr,
                         int* __restrict__ cursor, int* __restrict__ csr_src,
                         float* __restrict__ csr_w, int e, int n0) {
  int i = blockIdx.x * blockDim.x + threadIdx.x;
  if (i >= 2 * e) return;
  int s, d;
  if (i < e) { s = ei1[i];          d = ei1[i + e]; }
  else       { s = ei2[i - e] + n0; d = ei2[i] + n0; }   // ei2[i-e+e]
  int pos = atomicAdd(&cursor[d], 1);
  int idx = row_ptr[d] + pos;
  csr_src[idx] = s;
  csr_w[idx] = dinv[s] * dinv[d];
}

// ---------- MFMA bf16 GEMM: C[M,256] = A[M,K] @ W  (Wt packed [K/8][256][8]) ----------
__global__ __launch_bounds__(256) void k_gemm_bf(const unsigned short* __restrict__ A,
                                                 const unsigned short* __restrict__ Wt,
                                                 unsigned short* __restrict__ C,
                                                 int K) {
  const int w = threadIdx.x >> 6;
  const int lane = threadIdx.x & 63;
  const int bm = blockIdx.x * 64 + w * 16;
  const int bn = blockIdx.y * 128;
  const int row = bm + (lane & 15);
  const int kg0 = lane >> 4;
  f32x4 acc[8];
#pragma unroll
  for (int i = 0; i < 8; ++i) acc[i] = (f32x4){0.f, 0.f, 0.f, 0.f};

  const unsigned short* arow = A + (size_t)row * K + kg0 * 8;
  for (int k0 = 0; k0 < K; k0 += 32) {
    bf16x8 a = *(const bf16x8*)(arow + k0);
    const unsigned short* bbase =
        Wt + (((size_t)((k0 >> 3) + kg0) * HD) + bn + (lane & 15)) * 8;
#pragma unroll
    for (int nt = 0; nt < 8; ++nt) {
      bf16x8 b = *(const bf16x8*)(bbase + (size_t)nt * 16 * 8);
      acc[nt] = __builtin_amdgcn_mfma_f32_16x16x32_bf16(a, b, acc[nt], 0, 0, 0);
    }
  }
  const int crow = bm + (lane >> 4) * 4;
  const int ccol = bn + (lane & 15);
#pragma unroll
  for (int nt = 0; nt < 8; ++nt)
#pragma unroll
    for (int r = 0; r < 4; ++r)
      C[(size_t)(crow + r) * HD + ccol + nt * 16] = f2bf(acc[nt][r]);
}

// ---------- fused gather (bf16 rows) ----------
__global__ __launch_bounds__(256) void k_gather_bf(const unsigned short* __restrict__ xw,
                                                   const int* __restrict__ row_ptr,
                                                   const int* __restrict__ csr_src,
                                                   const float* __restrict__ csr_w,
                                                   const float* __restrict__ dinv,
                                                   const float4* __restrict__ bias,
                                                   unsigned short* __restrict__ out, int n) {
  int node = (blockIdx.x * blockDim.x + threadIdx.x) >> 6;
  int lane = threadIdx.x & 63;
  if (node >= n) return;
  float di = dinv[node];
  float c = di * di;
  ushort4 xv = reinterpret_cast<const ushort4*>(xw + (size_t)node * HD)[lane];
  float4 bb = bias[lane];
  float ax = bb.x + c * bf2f(xv.x);
  float ay = bb.y + c * bf2f(xv.y);
  float az = bb.z + c * bf2f(xv.z);
  float aw = bb.w + c * bf2f(xv.w);
  float bx = 0.f, by = 0.f, bz = 0.f, bw = 0.f;
  int e = row_ptr[node], end = row_ptr[node + 1];
  for (; e + 2 <= end; e += 2) {
    int s0 = csr_src[e], s1 = csr_src[e + 1];
    float w0 = csr_w[e], w1 = csr_w[e + 1];
    ushort4 v0 = reinterpret_cast<const ushort4*>(xw + (size_t)s0 * HD)[lane];
    ushort4 v1 = reinterpret_cast<const ushort4*>(xw + (size_t)s1 * HD)[lane];
    ax = fmaf(w0, bf2f(v0.x), ax); ay = fmaf(w0, bf2f(v0.y), ay);
    az = fmaf(w0, bf2f(v0.z), az); aw = fmaf(w0, bf2f(v0.w), aw);
    bx = fmaf(w1, bf2f(v1.x), bx); by = fmaf(w1, bf2f(v1.y), by);
    bz = fmaf(w1, bf2f(v1.z), bz); bw = fmaf(w1, bf2f(v1.w), bw);
  }
  if (e < end) {
    int s0 = csr_src[e];
    float w0 = csr_w[e];
    ushort4 v0 = reinterpret_cast<const ushort4*>(xw + (size_t)s0 * HD)[lane];
    ax = fmaf(w0, bf2f(v0.x), ax); ay = fmaf(w0, bf2f(v0.y), ay);
    az = fmaf(w0, bf2f(v0.z), az); aw = fmaf(w0, bf2f(v0.w), aw);
  }
  ax += bx; ay += by; az += bz; aw += bw;
  ushort4 o;
  o.x = f2bf(fmaxf(ax, 0.f)); o.y = f2bf(fmaxf(ay, 0.f));
  o.z = f2bf(fmaxf(az, 0.f)); o.w = f2bf(fmaxf(aw, 0.f));
  reinterpret_cast<ushort4*>(out + (size_t)node * HD)[lane] = o;
}

// ---------- pool over merged node space ----------
__global__ __launch_bounds__(256) void k_pool4(const unsigned short* __restrict__ h,
                                               const int* __restrict__ batch1,
                                               const int* __restrict__ batch2,
                                               float* __restrict__ scores,
                                               int n, int n0) {
  int wave = (blockIdx.x * blockDim.x + threadIdx.x) >> 6;
  int lane = threadIdx.x & 63;
  int beg = wave * 32;
  if (beg >= n) return;
  int end = min(beg + 32, n);
  bool g1 = beg >= n0;
  const int* bat = g1 ? batch2 : batch1;
  int boff = g1 ? n0 : 0;
  int coff = g1 ? HD : 0;
  float ax = 0.f, ay = 0.f, az = 0.f, aw = 0.f;
  int cur = bat[beg - boff];
  for (int i = beg; i < end; ++i) {
    int b = bat[i - boff];
    if (b != cur) {
      float* srow = &scores[(size_t)cur * 512 + coff + lane * 4];
      atomicAdd(&srow[0], ax); atomicAdd(&srow[1], ay);
      atomicAdd(&srow[2], az); atomicAdd(&srow[3], aw);
      ax = ay = az = aw = 0.f;
      cur = b;
    }
    ushort4 v = reinterpret_cast<const ushort4*>(h + (size_t)i * HD)[lane];
    ax += bf2f(v.x); ay += bf2f(v.y); az += bf2f(v.z); aw += bf2f(v.w);
  }
  float* srow = &scores[(size_t)cur * 512 + coff + lane * 4];
  atomicAdd(&srow[0], ax); atomicAdd(&srow[1], ay);
  atomicAdd(&srow[2], az); atomicAdd(&srow[3], aw);
}

// ---------- fused MLP head ----------
__global__ __launch_bounds__(256) void k_head(const float* __restrict__ scores,
                                              const float* __restrict__ lw0, const float* __restrict__ lb0,
                                              const float* __restrict__ lw1, const float* __restrict__ lb1,
                                              const float* __restrict__ lw2, const float* __restrict__ lb2,
                                              float* __restrict__ out) {
  __shared__ float s_in[512];
  __shared__ float s_h1[256];
  __shared__ float s_h2[128];
  __shared__ float red[4];
  const int r = blockIdx.x;
  const int t = threadIdx.x;
  s_in[t]       = scores[(size_t)r * 512 + t];
  s_in[t + 256] = scores[(size_t)r * 512 + t + 256];
  __syncthreads();
  float acc = lb0[t];
#pragma unroll 8
  for (int k = 0; k < 512; ++k) acc = fmaf(s_in[k], lw0[k * 256 + t], acc);
  s_h1[t] = fmaxf(acc, 0.f);
  __syncthreads();
  if (t < 128) {
    float a = lb1[t];
#pragma unroll 8
    for (int k = 0; k < 256; ++k) a = fmaf(s_h1[k], lw1[k * 128 + t], a);
    s_h2[t] = fmaxf(a, 0.f);
  }
  __syncthreads();
  float p = (t < 128) ? s_h2[t] * lw2[t] : 0.f;
#pragma unroll
  for (int off = 32; off; off >>= 1) p += __shfl_down(p, off);
  if ((t & 63) == 0) red[t >> 6] = p;
  __syncthreads();
  if (t == 0) {
    float z = red[0] + red[1] + red[2] + red[3] + lb2[0];
    out[r] = 1.f / (1.f + expf(-z));
  }
}

extern "C" void kernel_launch(void* const* d_in, const int* in_sizes, int n_in,
                              void* d_out, int out_size, void* d_ws, size_t ws_size,
                              hipStream_t stream) {
  const float* x1 = (const float*)d_in[0];
  const float* x2 = (const float*)d_in[1];
  const int* ei1 = (const int*)d_in[2];
  const int* ei2 = (const int*)d_in[3];
  const int* batch1 = (const int*)d_in[4];
  const int* batch2 = (const int*)d_in[5];
  const float* W0 = (const float*)d_in[6];  const float* b0 = (const float*)d_in[7];
  const float* W1 = (const float*)d_in[8];  const float* b1 = (const float*)d_in[9];
  const float* W2 = (const float*)d_in[10]; const float* b2 = (const float*)d_in[11];
  const float* lw0 = (const float*)d_in[12]; const float* lb0 = (const float*)d_in[13];
  const float* lw1 = (const float*)d_in[14]; const float* lb1 = (const float*)d_in[15];
  const float* lw2 = (const float*)d_in[16]; const float* lb2 = (const float*)d_in[17];
  float* out = (float*)d_out;

  const int N = in_sizes[0] / 128;   // 20000
  const int E = in_sizes[2] / 2;     // 320000
  const int N2 = 2 * N, E2 = 2 * E;
  const int NB = (N2 + 255) / 256;   // scan blocks

  char* p = (char*)d_ws;
  unsigned short* x_bf = (unsigned short*)p; p += (size_t)N2 * 128 * 2;
  unsigned short* buf0 = (unsigned short*)p; p += (size_t)N2 * HD * 2;
  unsigned short* buf1 = (unsigned short*)p; p += (size_t)N2 * HD * 2;
  unsigned short* Wt0  = (unsigned short*)p; p += (size_t)128 * HD * 2;
  unsigned short* Wt1  = (unsigned short*)p; p += (size_t)HD * HD * 2;
  unsigned short* Wt2  = (unsigned short*)p; p += (size_t)HD * HD * 2;
  float* dinv   = (float*)p; p += (size_t)N2 * 4;
  float* csr_w  = (float*)p; p += (size_t)E2 * 4;
  float* scores = (float*)p; p += (size_t)GB * 512 * 4;
  int* deg     = (int*)p; p += (size_t)N2 * 4;
  int* row_ptr = (int*)p; p += (size_t)(N2 + 1) * 4;
  int* cursor  = (int*)p; p += (size_t)N2 * 4;
  int* csr_src = (int*)p; p += (size_t)E2 * 4;
  int* partial = (int*)p; p += 256 * 4;

  // weight packing + input conversion
  k_prep_w<<<(128 * HD + 255) / 256, 256, 0, stream>>>(W0, Wt0, 128);
  k_prep_w<<<(HD * HD + 255) / 256, 256, 0, stream>>>(W1, Wt1, HD);
  k_prep_w<<<(HD * HD + 255) / 256, 256, 0, stream>>>(W2, Wt2, HD);
  int n4 = N * 128 / 4;
  k_cvt2<<<(2 * n4 + 255) / 256, 256, 0, stream>>>(
      (const float4*)x1, (const float4*)x2, (ushort4*)x_bf, n4);
  k_fill<<<(GB * 512 + 255) / 256, 256, 0, stream>>>(scores, GB * 512, 0.f);

  // merged CSR
  k_fill_i<<<(N2 + 255) / 256, 256, 0, stream>>>(deg, N2, 0);
  k_deg2<<<(2 * E + 255) / 256, 256, 0, stream>>>(ei1 + E, ei2 + E, deg, E, N);
  k_scan_a<<<NB, 256, 0, stream>>>(deg, partial, N2);
  k_scan_b<<<1, 256, 0, stream>>>(partial, NB, row_ptr, N2, E2);
  k_scan_c<<<NB, 256, 0, stream>>>(deg, partial, row_ptr, dinv, N2);
  k_fill_i<<<(N2 + 255) / 256, 256, 0, stream>>>(cursor, N2, 0);
  k_build2<<<(2 * E + 255) / 256, 256, 0, stream>>>(ei1, ei2, dinv, row_ptr,
                                                    cursor, csr_src, csr_w, E, N);

  // 3 GCN layers over the merged 40000-node problem
  dim3 ggrid(N2 / 64, 2);
  k_gemm_bf<<<ggrid, 256, 0, stream>>>(x_bf, Wt0, buf0, 128);
  k_gather_bf<<<(N2 + 3) / 4, 256, 0, stream>>>(buf0, row_ptr, csr_src, csr_w,
                                                dinv, (const float4*)b0, buf1, N2);
  k_gemm_bf<<<ggrid, 256, 0, stream>>>(buf1, Wt1, buf0, HD);
  k_gather_bf<<<(N2 + 3) / 4, 256, 0, stream>>>(buf0, row_ptr, csr_src, csr_w,
                                                dinv, (const float4*)b1, buf1, N2);
  k_gemm_bf<<<ggrid, 256, 0, stream>>>(buf1, Wt2, buf0, HD);
  k_gather_bf<<<(N2 + 3) / 4, 256, 0, stream>>>(buf0, row_ptr, csr_src, csr_w,
                                                dinv, (const float4*)b2, buf1, N2);

  int waves = N2 / 32;
  k_pool4<<<(waves + 3) / 4, 256, 0, stream>>>(buf1, batch1, batch2, scores, N2, N);
  k_head<<<GB, 256, 0, stream>>>(scores, lw0, lb0, lw1, lb1, lw2, lb2, out);
}

// Round 7
// 291.710 us; speedup vs baseline: 24.1644x; 1.2057x over previous
//
#include <hip/hip_runtime.h>
#include <hip/hip_bf16.h>
#include <math.h>

#define HD 256
#define GB 128

typedef __attribute__((ext_vector_type(8))) short bf16x8;
typedef __attribute__((ext_vector_type(4))) float f32x4;

__device__ __forceinline__ float bf2f(unsigned short u) {
  return __uint_as_float(((unsigned int)u) << 16);
}
__device__ __forceinline__ unsigned short f2bf(float f) {
  unsigned int u = __float_as_uint(f);
  unsigned int r = u + 0x7FFFu + ((u >> 16) & 1u);
  return (unsigned short)(r >> 16);
}

// ---------- merged prep: pack W0,W1,W2 into MFMA-friendly layout ----------
__global__ void k_prep3(const float* __restrict__ W0, const float* __restrict__ W1,
                        const float* __restrict__ W2, unsigned short* __restrict__ Wt0,
                        unsigned short* __restrict__ Wt1, unsigned short* __restrict__ Wt2) {
  int i = blockIdx.x * blockDim.x + threadIdx.x;
  const float* W; unsigned short* Wt; int j;
  if (i < 32768)       { W = W0; Wt = Wt0; j = i; }
  else if (i < 98304)  { W = W1; Wt = Wt1; j = i - 32768; }
  else if (i < 163840) { W = W2; Wt = Wt2; j = i - 98304; }
  else return;
  int k = j >> 8, c = j & 255;
  Wt[(((size_t)(k >> 3) * HD) + c) * 8 + (k & 7)] = f2bf(W[(size_t)k * HD + c]);
}

// fp32 -> bf16 for both inputs in one grid
__global__ void k_cvt2(const float4* __restrict__ in1, const float4* __restrict__ in2,
                       ushort4* __restrict__ out, int n4) {
  int i = blockIdx.x * blockDim.x + threadIdx.x;
  if (i >= 2 * n4) return;
  float4 v = (i < n4) ? in1[i] : in2[i - n4];
  ushort4 o;
  o.x = f2bf(v.x); o.y = f2bf(v.y); o.z = f2bf(v.z); o.w = f2bf(v.w);
  out[i] = o;
}

// zero scores + deg in one launch
__global__ void k_zero(float* __restrict__ scores, int* __restrict__ deg, int ns, int nd) {
  int i = blockIdx.x * blockDim.x + threadIdx.x;
  if (i < ns) scores[i] = 0.f;
  else if (i < ns + nd) deg[i - ns] = 0;
}

__global__ void k_deg2(const int* __restrict__ dst1, const int* __restrict__ dst2,
                       int* __restrict__ deg, int e, int n0) {
  int i = blockIdx.x * blockDim.x + threadIdx.x;
  if (i >= 2 * e) return;
  int d = (i < e) ? dst1[i] : (dst2[i - e] + n0);
  atomicAdd(&deg[d], 1);
}

// ---------- 3-phase scan ----------
__global__ __launch_bounds__(256) void k_scan_a(const int* __restrict__ deg,
                                                int* __restrict__ partial, int n) {
  __shared__ int sh[256];
  int i = blockIdx.x * 256 + threadIdx.x;
  int v = (i < n) ? deg[i] : 0;
  sh[threadIdx.x] = v;
  __syncthreads();
#pragma unroll
  for (int off = 128; off; off >>= 1) {
    if (threadIdx.x < off) sh[threadIdx.x] += sh[threadIdx.x + off];
    __syncthreads();
  }
  if (threadIdx.x == 0) partial[blockIdx.x] = sh[0];
}

__global__ __launch_bounds__(256) void k_scan_b(int* __restrict__ partial, int nb,
                                                int* __restrict__ row_ptr, int n, int e_total) {
  __shared__ int sh[256];
  int t = threadIdx.x;
  int v = (t < nb) ? partial[t] : 0;
  sh[t] = v;
  __syncthreads();
#pragma unroll
  for (int off = 1; off < 256; off <<= 1) {
    int u = (t >= off) ? sh[t - off] : 0;
    __syncthreads();
    sh[t] += u;
    __syncthreads();
  }
  if (t < nb) partial[t] = sh[t] - v;
  if (t == 0) row_ptr[n] = e_total;
}

__global__ __launch_bounds__(256) void k_scan_c(const int* __restrict__ deg,
                                                const int* __restrict__ partial,
                                                int* __restrict__ row_ptr,
                                                float* __restrict__ dinv,
                                                int* __restrict__ cursor, int n) {
  __shared__ int sh[256];
  int i = blockIdx.x * 256 + threadIdx.x;
  int t = threadIdx.x;
  int v = (i < n) ? deg[i] : 0;
  sh[t] = v;
  __syncthreads();
#pragma unroll
  for (int off = 1; off < 256; off <<= 1) {
    int u = (t >= off) ? sh[t - off] : 0;
    __syncthreads();
    sh[t] += u;
    __syncthreads();
  }
  if (i < n) {
    row_ptr[i] = sh[t] - v + partial[blockIdx.x];
    dinv[i] = rsqrtf((float)(v + 1));
    cursor[i] = 0;
  }
}

// CSR build (interleaved int2: .x = src, .y = float bits of weight)
__global__ void k_build2(const int* __restrict__ ei1, const int* __restrict__ ei2,
                         const float* __restrict__ dinv, const int* __restrict__ row_ptr,
                         int* __restrict__ cursor, int2* __restrict__ csr, int e, int n0) {
  int i = blockIdx.x * blockDim.x + threadIdx.x;
  if (i >= 2 * e) return;
  int s, d;
  if (i < e) { s = ei1[i];          d = ei1[i + e]; }
  else       { s = ei2[i - e] + n0; d = ei2[i] + n0; }
  int pos = atomicAdd(&cursor[d], 1);
  int idx = row_ptr[d] + pos;
  csr[idx] = make_int2(s, __float_as_int(dinv[s] * dinv[d]));
}

// ---------- MFMA bf16 GEMM: C[M,256] = A[M,K] @ W, optional bias+relu ----------
template<bool BR>
__global__ __launch_bounds__(256) void k_gemm_bf(const unsigned short* __restrict__ A,
                                                 const unsigned short* __restrict__ Wt,
                                                 const float* __restrict__ bias,
                                                 unsigned short* __restrict__ C,
                                                 int K) {
  const int w = threadIdx.x >> 6;
  const int lane = threadIdx.x & 63;
  const int bm = blockIdx.x * 64 + w * 16;
  const int bn = blockIdx.y * 128;
  const int row = bm + (lane & 15);
  const int kg0 = lane >> 4;
  f32x4 acc[8];
#pragma unroll
  for (int i = 0; i < 8; ++i) acc[i] = (f32x4){0.f, 0.f, 0.f, 0.f};

  const unsigned short* arow = A + (size_t)row * K + kg0 * 8;
  for (int k0 = 0; k0 < K; k0 += 32) {
    bf16x8 a = *(const bf16x8*)(arow + k0);
    const unsigned short* bbase =
        Wt + (((size_t)((k0 >> 3) + kg0) * HD) + bn + (lane & 15)) * 8;
#pragma unroll
    for (int nt = 0; nt < 8; ++nt) {
      bf16x8 b = *(const bf16x8*)(bbase + (size_t)nt * 16 * 8);
      acc[nt] = __builtin_amdgcn_mfma_f32_16x16x32_bf16(a, b, acc[nt], 0, 0, 0);
    }
  }
  const int crow = bm + (lane >> 4) * 4;
  const int ccol = bn + (lane & 15);
#pragma unroll
  for (int nt = 0; nt < 8; ++nt) {
    float bb = BR ? bias[ccol + nt * 16] : 0.f;
#pragma unroll
    for (int r = 0; r < 4; ++r) {
      float v = acc[nt][r];
      if (BR) v = fmaxf(v + bb, 0.f);
      C[(size_t)(crow + r) * HD + ccol + nt * 16] = f2bf(v);
    }
  }
}

// ---------- row loader (templated — the round-6 bug was overloads on decayed arrays) ----------
template<int FB>
__device__ __forceinline__ void load_row(const unsigned short* p, float (&f)[FB]) {
  if constexpr (FB == 4) {
    ushort4 v = *(const ushort4*)p;
    f[0] = bf2f(v.x); f[1] = bf2f(v.y); f[2] = bf2f(v.z); f[3] = bf2f(v.w);
  } else {
    ushort2 v = *(const ushort2*)p;
    f[0] = bf2f(v.x); f[1] = bf2f(v.y);
  }
}

// ---------- fused gather, FB bf16 elems per lane (F = FB*64), optional bias+relu ----------
template<int FB, bool BR>
__global__ __launch_bounds__(256) void k_gath(const unsigned short* __restrict__ xw,
                                              const int* __restrict__ row_ptr,
                                              const int2* __restrict__ csr,
                                              const float* __restrict__ dinv,
                                              const float* __restrict__ bias,
                                              unsigned short* __restrict__ out, int n) {
  constexpr int F = FB * 64;
  int node = (blockIdx.x * blockDim.x + threadIdx.x) >> 6;
  int lane = threadIdx.x & 63;
  if (node >= n) return;
  float di = dinv[node];
  float c = di * di;
  float self[FB], acc0[FB], acc1[FB];
  load_row<FB>(xw + (size_t)node * F + lane * FB, self);
#pragma unroll
  for (int q = 0; q < FB; ++q) { acc0[q] = c * self[q]; acc1[q] = 0.f; }

  int e = row_ptr[node], end = row_ptr[node + 1];
  while (e < end) {
    int cnt = min(end - e, 64);
    int2 ew = make_int2(0, 0);
    if (lane < cnt) ew = csr[e + lane];
    int j = 0;
    for (; j + 4 <= cnt; j += 4) {
      int s0 = __shfl(ew.x, j + 0), s1 = __shfl(ew.x, j + 1);
      int s2 = __shfl(ew.x, j + 2), s3 = __shfl(ew.x, j + 3);
      float w0 = __int_as_float(__shfl(ew.y, j + 0));
      float w1 = __int_as_float(__shfl(ew.y, j + 1));
      float w2 = __int_as_float(__shfl(ew.y, j + 2));
      float w3 = __int_as_float(__shfl(ew.y, j + 3));
      float r0[FB], r1[FB], r2[FB], r3[FB];
      load_row<FB>(xw + (size_t)s0 * F + lane * FB, r0);
      load_row<FB>(xw + (size_t)s1 * F + lane * FB, r1);
      load_row<FB>(xw + (size_t)s2 * F + lane * FB, r2);
      load_row<FB>(xw + (size_t)s3 * F + lane * FB, r3);
#pragma unroll
      for (int q = 0; q < FB; ++q) {
        acc0[q] = fmaf(w0, r0[q], acc0[q]);
        acc1[q] = fmaf(w1, r1[q], acc1[q]);
        acc0[q] = fmaf(w2, r2[q], acc0[q]);
        acc1[q] = fmaf(w3, r3[q], acc1[q]);
      }
    }
    for (; j < cnt; ++j) {
      int s0 = __shfl(ew.x, j);
      float w0 = __int_as_float(__shfl(ew.y, j));
      float r0[FB];
      load_row<FB>(xw + (size_t)s0 * F + lane * FB, r0);
#pragma unroll
      for (int q = 0; q < FB; ++q) acc0[q] = fmaf(w0, r0[q], acc0[q]);
    }
    e += cnt;
  }
  unsigned short o[FB];
#pragma unroll
  for (int q = 0; q < FB; ++q) {
    float v = acc0[q] + acc1[q];
    if (BR) v = fmaxf(v + bias[lane * FB + q], 0.f);
    o[q] = f2bf(v);
  }
  if constexpr (FB == 4) {
    ushort4 ov; ov.x = o[0]; ov.y = o[1]; ov.z = o[2]; ov.w = o[3];
    *(ushort4*)(out + (size_t)node * F + lane * FB) = ov;
  } else {
    ushort2 ov; ov.x = o[0]; ov.y = o[1];
    *(ushort2*)(out + (size_t)node * F + lane * FB) = ov;
  }
}

// ---------- pool over merged node space ----------
__global__ __launch_bounds__(256) void k_pool4(const unsigned short* __restrict__ h,
                                               const int* __restrict__ batch1,
                                               const int* __restrict__ batch2,
                                               float* __restrict__ scores,
                                               int n, int n0) {
  int wave = (blockIdx.x * blockDim.x + threadIdx.x) >> 6;
  int lane = threadIdx.x & 63;
  int beg = wave * 32;
  if (beg >= n) return;
  int end = min(beg + 32, n);
  bool g1 = beg >= n0;
  const int* bat = g1 ? batch2 : batch1;
  int boff = g1 ? n0 : 0;
  int coff = g1 ? HD : 0;
  float ax = 0.f, ay = 0.f, az = 0.f, aw = 0.f;
  int cur = bat[beg - boff];
  for (int i = beg; i < end; ++i) {
    int b = bat[i - boff];
    if (b != cur) {
      float* srow = &scores[(size_t)cur * 512 + coff + lane * 4];
      atomicAdd(&srow[0], ax); atomicAdd(&srow[1], ay);
      atomicAdd(&srow[2], az); atomicAdd(&srow[3], aw);
      ax = ay = az = aw = 0.f;
      cur = b;
    }
    ushort4 v = reinterpret_cast<const ushort4*>(h + (size_t)i * HD)[lane];
    ax += bf2f(v.x); ay += bf2f(v.y); az += bf2f(v.z); aw += bf2f(v.w);
  }
  float* srow = &scores[(size_t)cur * 512 + coff + lane * 4];
  atomicAdd(&srow[0], ax); atomicAdd(&srow[1], ay);
  atomicAdd(&srow[2], az); atomicAdd(&srow[3], aw);
}

// ---------- fused MLP head ----------
__global__ __launch_bounds__(256) void k_head(const float* __restrict__ scores,
                                              const float* __restrict__ lw0, const float* __restrict__ lb0,
                                              const float* __restrict__ lw1, const float* __restrict__ lb1,
                                              const float* __restrict__ lw2, const float* __restrict__ lb2,
                                              float* __restrict__ out) {
  __shared__ float s_in[512];
  __shared__ float s_h1[256];
  __shared__ float s_h2[128];
  __shared__ float red[4];
  const int r = blockIdx.x;
  const int t = threadIdx.x;
  s_in[t]       = scores[(size_t)r * 512 + t];
  s_in[t + 256] = scores[(size_t)r * 512 + t + 256];
  __syncthreads();
  float acc = lb0[t];
#pragma unroll 8
  for (int k = 0; k < 512; ++k) acc = fmaf(s_in[k], lw0[k * 256 + t], acc);
  s_h1[t] = fmaxf(acc, 0.f);
  __syncthreads();
  if (t < 128) {
    float a = lb1[t];
#pragma unroll 8
    for (int k = 0; k < 256; ++k) a = fmaf(s_h1[k], lw1[k * 128 + t], a);
    s_h2[t] = fmaxf(a, 0.f);
  }
  __syncthreads();
  float p = (t < 128) ? s_h2[t] * lw2[t] : 0.f;
#pragma unroll
  for (int off = 32; off; off >>= 1) p += __shfl_down(p, off);
  if ((t & 63) == 0) red[t >> 6] = p;
  __syncthreads();
  if (t == 0) {
    float z = red[0] + red[1] + red[2] + red[3] + lb2[0];
    out[r] = 1.f / (1.f + expf(-z));
  }
}

extern "C" void kernel_launch(void* const* d_in, const int* in_sizes, int n_in,
                              void* d_out, int out_size, void* d_ws, size_t ws_size,
                              hipStream_t stream) {
  const float* x1 = (const float*)d_in[0];
  const float* x2 = (const float*)d_in[1];
  const int* ei1 = (const int*)d_in[2];
  const int* ei2 = (const int*)d_in[3];
  const int* batch1 = (const int*)d_in[4];
  const int* batch2 = (const int*)d_in[5];
  const float* W0 = (const float*)d_in[6];  const float* b0 = (const float*)d_in[7];
  const float* W1 = (const float*)d_in[8];  const float* b1 = (const float*)d_in[9];
  const float* W2 = (const float*)d_in[10]; const float* b2 = (const float*)d_in[11];
  const float* lw0 = (const float*)d_in[12]; const float* lb0 = (const float*)d_in[13];
  const float* lw1 = (const float*)d_in[14]; const float* lb1 = (const float*)d_in[15];
  const float* lw2 = (const float*)d_in[16]; const float* lb2 = (const float*)d_in[17];
  float* out = (float*)d_out;

  const int N = in_sizes[0] / 128;   // 20000
  const int E = in_sizes[2] / 2;     // 320000
  const int N2 = 2 * N, E2 = 2 * E;
  const int NB = (N2 + 255) / 256;

  char* p = (char*)d_ws;
  unsigned short* x_bf = (unsigned short*)p; p += (size_t)N2 * 128 * 2;
  unsigned short* aggx = (unsigned short*)p; p += (size_t)N2 * 128 * 2;
  unsigned short* buf0 = (unsigned short*)p; p += (size_t)N2 * HD * 2;
  unsigned short* buf1 = (unsigned short*)p; p += (size_t)N2 * HD * 2;
  unsigned short* Wt0  = (unsigned short*)p; p += (size_t)128 * HD * 2;
  unsigned short* Wt1  = (unsigned short*)p; p += (size_t)HD * HD * 2;
  unsigned short* Wt2  = (unsigned short*)p; p += (size_t)HD * HD * 2;
  float* dinv   = (float*)p; p += (size_t)N2 * 4;
  float* scores = (float*)p; p += (size_t)GB * 512 * 4;
  int2* csr    = (int2*)p; p += (size_t)E2 * 8;
  int* deg     = (int*)p; p += (size_t)N2 * 4;
  int* row_ptr = (int*)p; p += (size_t)(N2 + 1) * 4;
  int* cursor  = (int*)p; p += (size_t)N2 * 4;
  int* partial = (int*)p; p += 256 * 4;

  // prep
  k_prep3<<<(163840 + 255) / 256, 256, 0, stream>>>(W0, W1, W2, Wt0, Wt1, Wt2);
  int n4 = N * 128 / 4;
  k_cvt2<<<(2 * n4 + 255) / 256, 256, 0, stream>>>(
      (const float4*)x1, (const float4*)x2, (ushort4*)x_bf, n4);
  k_zero<<<(GB * 512 + N2 + 255) / 256, 256, 0, stream>>>(scores, deg, GB * 512, N2);

  // merged CSR
  k_deg2<<<(2 * E + 255) / 256, 256, 0, stream>>>(ei1 + E, ei2 + E, deg, E, N);
  k_scan_a<<<NB, 256, 0, stream>>>(deg, partial, N2);
  k_scan_b<<<1, 256, 0, stream>>>(partial, NB, row_ptr, N2, E2);
  k_scan_c<<<NB, 256, 0, stream>>>(deg, partial, row_ptr, dinv, cursor, N2);
  k_build2<<<(2 * E + 255) / 256, 256, 0, stream>>>(ei1, ei2, dinv, row_ptr,
                                                    cursor, csr, E, N);

  dim3 ggrid(N2 / 64, 2);
  // layer 0: aggregate x (128-dim) first, then GEMM with bias+relu
  k_gath<2, false><<<(N2 + 3) / 4, 256, 0, stream>>>(x_bf, row_ptr, csr, dinv,
                                                     nullptr, aggx, N2);
  k_gemm_bf<true><<<ggrid, 256, 0, stream>>>(aggx, Wt0, b0, buf0, 128);
  // layer 1
  k_gemm_bf<false><<<ggrid, 256, 0, stream>>>(buf0, Wt1, nullptr, buf1, HD);
  k_gath<4, true><<<(N2 + 3) / 4, 256, 0, stream>>>(buf1, row_ptr, csr, dinv,
                                                    b1, buf0, N2);
  // layer 2
  k_gemm_bf<false><<<ggrid, 256, 0, stream>>>(buf0, Wt2, nullptr, buf1, HD);
  k_gath<4, true><<<(N2 + 3) / 4, 256, 0, stream>>>(buf1, row_ptr, csr, dinv,
                                                    b2, buf0, N2);

  int waves = N2 / 32;
  k_pool4<<<(waves + 3) / 4, 256, 0, stream>>>(buf0, batch1, batch2, scores, N2, N);
  k_head<<<GB, 256, 0, stream>>>(scores, lw0, lb0, lw1, lb1, lw2, lb2, out);
}

// Round 8
// 273.338 us; speedup vs baseline: 25.7886x; 1.0672x over previous
//
#include <hip/hip_runtime.h>
#include <hip/hip_bf16.h>
#include <math.h>

#define HD 256
#define GB 128

typedef __attribute__((ext_vector_type(8))) short bf16x8;
typedef __attribute__((ext_vector_type(4))) float f32x4;

__device__ __forceinline__ float bf2f(unsigned short u) {
  return __uint_as_float(((unsigned int)u) << 16);
}
__device__ __forceinline__ unsigned short f2bf(float f) {
  unsigned int u = __float_as_uint(f);
  unsigned int r = u + 0x7FFFu + ((u >> 16) & 1u);
  return (unsigned short)(r >> 16);
}

// ---------- merged prep: pack W0,W1,W2 into MFMA-friendly layout ----------
__global__ void k_prep3(const float* __restrict__ W0, const float* __restrict__ W1,
                        const float* __restrict__ W2, unsigned short* __restrict__ Wt0,
                        unsigned short* __restrict__ Wt1, unsigned short* __restrict__ Wt2) {
  int i = blockIdx.x * blockDim.x + threadIdx.x;
  const float* W; unsigned short* Wt; int j;
  if (i < 32768)       { W = W0; Wt = Wt0; j = i; }
  else if (i < 98304)  { W = W1; Wt = Wt1; j = i - 32768; }
  else if (i < 163840) { W = W2; Wt = Wt2; j = i - 98304; }
  else return;
  int k = j >> 8, c = j & 255;
  Wt[(((size_t)(k >> 3) * HD) + c) * 8 + (k & 7)] = f2bf(W[(size_t)k * HD + c]);
}

// fp32 -> bf16 for both inputs in one grid
__global__ void k_cvt2(const float4* __restrict__ in1, const float4* __restrict__ in2,
                       ushort4* __restrict__ out, int n4) {
  int i = blockIdx.x * blockDim.x + threadIdx.x;
  if (i >= 2 * n4) return;
  float4 v = (i < n4) ? in1[i] : in2[i - n4];
  ushort4 o;
  o.x = f2bf(v.x); o.y = f2bf(v.y); o.z = f2bf(v.z); o.w = f2bf(v.w);
  out[i] = o;
}

// zero scores + deg in one launch
__global__ void k_zero(float* __restrict__ scores, int* __restrict__ deg, int ns, int nd) {
  int i = blockIdx.x * blockDim.x + threadIdx.x;
  if (i < ns) scores[i] = 0.f;
  else if (i < ns + nd) deg[i - ns] = 0;
}

__global__ void k_deg2(const int* __restrict__ dst1, const int* __restrict__ dst2,
                       int* __restrict__ deg, int e, int n0) {
  int i = blockIdx.x * blockDim.x + threadIdx.x;
  if (i >= 2 * e) return;
  int d = (i < e) ? dst1[i] : (dst2[i - e] + n0);
  atomicAdd(&deg[d], 1);
}

// ---------- 3-phase scan ----------
__global__ __launch_bounds__(256) void k_scan_a(const int* __restrict__ deg,
                                                int* __restrict__ partial, int n) {
  __shared__ int sh[256];
  int i = blockIdx.x * 256 + threadIdx.x;
  int v = (i < n) ? deg[i] : 0;
  sh[threadIdx.x] = v;
  __syncthreads();
#pragma unroll
  for (int off = 128; off; off >>= 1) {
    if (threadIdx.x < off) sh[threadIdx.x] += sh[threadIdx.x + off];
    __syncthreads();
  }
  if (threadIdx.x == 0) partial[blockIdx.x] = sh[0];
}

__global__ __launch_bounds__(256) void k_scan_b(int* __restrict__ partial, int nb,
                                                int* __restrict__ row_ptr, int n, int e_total) {
  __shared__ int sh[256];
  int t = threadIdx.x;
  int v = (t < nb) ? partial[t] : 0;
  sh[t] = v;
  __syncthreads();
#pragma unroll
  for (int off = 1; off < 256; off <<= 1) {
    int u = (t >= off) ? sh[t - off] : 0;
    __syncthreads();
    sh[t] += u;
    __syncthreads();
  }
  if (t < nb) partial[t] = sh[t] - v;
  if (t == 0) row_ptr[n] = e_total;
}

__global__ __launch_bounds__(256) void k_scan_c(const int* __restrict__ deg,
                                                const int* __restrict__ partial,
                                                int* __restrict__ row_ptr,
                                                float* __restrict__ dinv,
                                                int* __restrict__ cursor, int n) {
  __shared__ int sh[256];
  int i = blockIdx.x * 256 + threadIdx.x;
  int t = threadIdx.x;
  int v = (i < n) ? deg[i] : 0;
  sh[t] = v;
  __syncthreads();
#pragma unroll
  for (int off = 1; off < 256; off <<= 1) {
    int u = (t >= off) ? sh[t - off] : 0;
    __syncthreads();
    sh[t] += u;
    __syncthreads();
  }
  if (i < n) {
    row_ptr[i] = sh[t] - v + partial[blockIdx.x];
    dinv[i] = rsqrtf((float)(v + 1));
    cursor[i] = 0;
  }
}

// CSR build (interleaved int2: .x = src, .y = float bits of weight)
__global__ void k_build2(const int* __restrict__ ei1, const int* __restrict__ ei2,
                         const float* __restrict__ dinv, const int* __restrict__ row_ptr,
                         int* __restrict__ cursor, int2* __restrict__ csr, int e, int n0) {
  int i = blockIdx.x * blockDim.x + threadIdx.x;
  if (i >= 2 * e) return;
  int s, d;
  if (i < e) { s = ei1[i];          d = ei1[i + e]; }
  else       { s = ei2[i - e] + n0; d = ei2[i] + n0; }
  int pos = atomicAdd(&cursor[d], 1);
  int idx = row_ptr[d] + pos;
  csr[idx] = make_int2(s, __float_as_int(dinv[s] * dinv[d]));
}

// ---------- MFMA bf16 GEMM: C[M,256] = A[M,K] @ W, optional bias+relu ----------
template<bool BR>
__global__ __launch_bounds__(256) void k_gemm_bf(const unsigned short* __restrict__ A,
                                                 const unsigned short* __restrict__ Wt,
                                                 const float* __restrict__ bias,
                                                 unsigned short* __restrict__ C,
                                                 int K) {
  const int w = threadIdx.x >> 6;
  const int lane = threadIdx.x & 63;
  const int bm = blockIdx.x * 64 + w * 16;
  const int bn = blockIdx.y * 128;
  const int row = bm + (lane & 15);
  const int kg0 = lane >> 4;
  f32x4 acc[8];
#pragma unroll
  for (int i = 0; i < 8; ++i) acc[i] = (f32x4){0.f, 0.f, 0.f, 0.f};

  const unsigned short* arow = A + (size_t)row * K + kg0 * 8;
  for (int k0 = 0; k0 < K; k0 += 32) {
    bf16x8 a = *(const bf16x8*)(arow + k0);
    const unsigned short* bbase =
        Wt + (((size_t)((k0 >> 3) + kg0) * HD) + bn + (lane & 15)) * 8;
#pragma unroll
    for (int nt = 0; nt < 8; ++nt) {
      bf16x8 b = *(const bf16x8*)(bbase + (size_t)nt * 16 * 8);
      acc[nt] = __builtin_amdgcn_mfma_f32_16x16x32_bf16(a, b, acc[nt], 0, 0, 0);
    }
  }
  const int crow = bm + (lane >> 4) * 4;
  const int ccol = bn + (lane & 15);
#pragma unroll
  for (int nt = 0; nt < 8; ++nt) {
    float bb = BR ? bias[ccol + nt * 16] : 0.f;
#pragma unroll
    for (int r = 0; r < 4; ++r) {
      float v = acc[nt][r];
      if (BR) v = fmaxf(v + bb, 0.f);
      C[(size_t)(crow + r) * HD + ccol + nt * 16] = f2bf(v);
    }
  }
}

// ---------- row loader ----------
template<int FB>
__device__ __forceinline__ void load_row(const unsigned short* p, float (&f)[FB]) {
  if constexpr (FB == 4) {
    ushort4 v = *(const ushort4*)p;
    f[0] = bf2f(v.x); f[1] = bf2f(v.y); f[2] = bf2f(v.z); f[3] = bf2f(v.w);
  } else {
    ushort2 v = *(const ushort2*)p;
    f[0] = bf2f(v.x); f[1] = bf2f(v.y);
  }
}

// ---------- fused gather, FB bf16 elems per lane (F = FB*64), optional bias+relu ----------
template<int FB, bool BR>
__global__ __launch_bounds__(256) void k_gath(const unsigned short* __restrict__ xw,
                                              const int* __restrict__ row_ptr,
                                              const int2* __restrict__ csr,
                                              const float* __restrict__ dinv,
                                              const float* __restrict__ bias,
                                              unsigned short* __restrict__ out, int n) {
  constexpr int F = FB * 64;
  int node = (blockIdx.x * blockDim.x + threadIdx.x) >> 6;
  int lane = threadIdx.x & 63;
  if (node >= n) return;
  float di = dinv[node];
  float c = di * di;
  float self[FB], acc0[FB], acc1[FB];
  load_row<FB>(xw + (size_t)node * F + lane * FB, self);
#pragma unroll
  for (int q = 0; q < FB; ++q) { acc0[q] = c * self[q]; acc1[q] = 0.f; }

  int e = row_ptr[node], end = row_ptr[node + 1];
  while (e < end) {
    int cnt = min(end - e, 64);
    int2 ew = make_int2(0, 0);
    if (lane < cnt) ew = csr[e + lane];
    int j = 0;
    for (; j + 4 <= cnt; j += 4) {
      int s0 = __shfl(ew.x, j + 0), s1 = __shfl(ew.x, j + 1);
      int s2 = __shfl(ew.x, j + 2), s3 = __shfl(ew.x, j + 3);
      float w0 = __int_as_float(__shfl(ew.y, j + 0));
      float w1 = __int_as_float(__shfl(ew.y, j + 1));
      float w2 = __int_as_float(__shfl(ew.y, j + 2));
      float w3 = __int_as_float(__shfl(ew.y, j + 3));
      float r0[FB], r1[FB], r2[FB], r3[FB];
      load_row<FB>(xw + (size_t)s0 * F + lane * FB, r0);
      load_row<FB>(xw + (size_t)s1 * F + lane * FB, r1);
      load_row<FB>(xw + (size_t)s2 * F + lane * FB, r2);
      load_row<FB>(xw + (size_t)s3 * F + lane * FB, r3);
#pragma unroll
      for (int q = 0; q < FB; ++q) {
        acc0[q] = fmaf(w0, r0[q], acc0[q]);
        acc1[q] = fmaf(w1, r1[q], acc1[q]);
        acc0[q] = fmaf(w2, r2[q], acc0[q]);
        acc1[q] = fmaf(w3, r3[q], acc1[q]);
      }
    }
    for (; j < cnt; ++j) {
      int s0 = __shfl(ew.x, j);
      float w0 = __int_as_float(__shfl(ew.y, j));
      float r0[FB];
      load_row<FB>(xw + (size_t)s0 * F + lane * FB, r0);
#pragma unroll
      for (int q = 0; q < FB; ++q) acc0[q] = fmaf(w0, r0[q], acc0[q]);
    }
    e += cnt;
  }
  unsigned short o[FB];
#pragma unroll
  for (int q = 0; q < FB; ++q) {
    float v = acc0[q] + acc1[q];
    if (BR) v = fmaxf(v + bias[lane * FB + q], 0.f);
    o[q] = f2bf(v);
  }
  if constexpr (FB == 4) {
    ushort4 ov; ov.x = o[0]; ov.y = o[1]; ov.z = o[2]; ov.w = o[3];
    *(ushort4*)(out + (size_t)node * F + lane * FB) = ov;
  } else {
    ushort2 ov; ov.x = o[0]; ov.y = o[1];
    *(ushort2*)(out + (size_t)node * F + lane * FB) = ov;
  }
}

// ---------- pool over merged node space ----------
__global__ __launch_bounds__(256) void k_pool4(const unsigned short* __restrict__ h,
                                               const int* __restrict__ batch1,
                                               const int* __restrict__ batch2,
                                               float* __restrict__ scores,
                                               int n, int n0) {
  int wave = (blockIdx.x * blockDim.x + threadIdx.x) >> 6;
  int lane = threadIdx.x & 63;
  int beg = wave * 32;
  if (beg >= n) return;
  int end = min(beg + 32, n);
  bool g1 = beg >= n0;
  const int* bat = g1 ? batch2 : batch1;
  int boff = g1 ? n0 : 0;
  int coff = g1 ? HD : 0;
  float ax = 0.f, ay = 0.f, az = 0.f, aw = 0.f;
  int cur = bat[beg - boff];
  for (int i = beg; i < end; ++i) {
    int b = bat[i - boff];
    if (b != cur) {
      float* srow = &scores[(size_t)cur * 512 + coff + lane * 4];
      atomicAdd(&srow[0], ax); atomicAdd(&srow[1], ay);
      atomicAdd(&srow[2], az); atomicAdd(&srow[3], aw);
      ax = ay = az = aw = 0.f;
      cur = b;
    }
    ushort4 v = reinterpret_cast<const ushort4*>(h + (size_t)i * HD)[lane];
    ax += bf2f(v.x); ay += bf2f(v.y); az += bf2f(v.z); aw += bf2f(v.w);
  }
  float* srow = &scores[(size_t)cur * 512 + coff + lane * 4];
  atomicAdd(&srow[0], ax); atomicAdd(&srow[1], ay);
  atomicAdd(&srow[2], az); atomicAdd(&srow[3], aw);
}

// ---------- head layer 0: h1[r, ct*64+c] = relu(lb0 + scores[r,:] . lw0[:, col]) ----------
// grid (GB, 4); wave w handles K-chunk [w*128, w*128+128), 64 cols each
__global__ __launch_bounds__(256) void k_head_a(const float* __restrict__ scores,
                                                const float* __restrict__ lw0,
                                                const float* __restrict__ lb0,
                                                float* __restrict__ h1) {
  __shared__ float s_in[512];
  __shared__ float part[4][64];
  const int r = blockIdx.x, ct = blockIdx.y;
  const int t = threadIdx.x;
  s_in[t]       = scores[(size_t)r * 512 + t];
  s_in[t + 256] = scores[(size_t)r * 512 + t + 256];
  __syncthreads();
  const int l = t & 63, w = t >> 6;
  const int col = ct * 64 + l;
  float acc = 0.f;
  const float* wp = lw0 + (size_t)(w * 128) * 256 + col;
  const float* sp = s_in + w * 128;
#pragma unroll 8
  for (int k = 0; k < 128; ++k) acc = fmaf(sp[k], wp[(size_t)k * 256], acc);
  part[w][l] = acc;
  __syncthreads();
  if (t < 64) {
    float v = part[0][t] + part[1][t] + part[2][t] + part[3][t] + lb0[ct * 64 + t];
    h1[(size_t)r * 256 + ct * 64 + t] = fmaxf(v, 0.f);
  }
}

// ---------- head layers 1+2: h2 = relu(h1@lw1+lb1); out = sigmoid(h2.lw2+lb2) ----------
__global__ __launch_bounds__(256) void k_head_b(const float* __restrict__ h1,
                                                const float* __restrict__ lw1,
                                                const float* __restrict__ lb1,
                                                const float* __restrict__ lw2,
                                                const float* __restrict__ lb2,
                                                float* __restrict__ out) {
  __shared__ float s_in[256];
  __shared__ float part[2][128];
  __shared__ float s_h2[128];
  __shared__ float red[4];
  const int r = blockIdx.x;
  const int t = threadIdx.x;
  s_in[t] = h1[(size_t)r * 256 + t];
  __syncthreads();
  const int l = t & 127, w = t >> 7;
  float acc = 0.f;
  const float* wp = lw1 + (size_t)(w * 128) * 128 + l;
  const float* sp = s_in + w * 128;
#pragma unroll 8
  for (int k = 0; k < 128; ++k) acc = fmaf(sp[k], wp[(size_t)k * 128], acc);
  part[w][l] = acc;
  __syncthreads();
  if (t < 128) s_h2[t] = fmaxf(part[0][t] + part[1][t] + lb1[t], 0.f);
  __syncthreads();
  float p = (t < 128) ? s_h2[t] * lw2[t] : 0.f;
#pragma unroll
  for (int off = 32; off; off >>= 1) p += __shfl_down(p, off);
  if ((t & 63) == 0) red[t >> 6] = p;
  __syncthreads();
  if (t == 0) {
    float z = red[0] + red[1] + red[2] + red[3] + lb2[0];
    out[r] = 1.f / (1.f + expf(-z));
  }
}

extern "C" void kernel_launch(void* const* d_in, const int* in_sizes, int n_in,
                              void* d_out, int out_size, void* d_ws, size_t ws_size,
                              hipStream_t stream) {
  const float* x1 = (const float*)d_in[0];
  const float* x2 = (const float*)d_in[1];
  const int* ei1 = (const int*)d_in[2];
  const int* ei2 = (const int*)d_in[3];
  const int* batch1 = (const int*)d_in[4];
  const int* batch2 = (const int*)d_in[5];
  const float* W0 = (const float*)d_in[6];  const float* b0 = (const float*)d_in[7];
  const float* W1 = (const float*)d_in[8];  const float* b1 = (const float*)d_in[9];
  const float* W2 = (const float*)d_in[10]; const float* b2 = (const float*)d_in[11];
  const float* lw0 = (const float*)d_in[12]; const float* lb0 = (const float*)d_in[13];
  const float* lw1 = (const float*)d_in[14]; const float* lb1 = (const float*)d_in[15];
  const float* lw2 = (const float*)d_in[16]; const float* lb2 = (const float*)d_in[17];
  float* out = (float*)d_out;

  const int N = in_sizes[0] / 128;   // 20000
  const int E = in_sizes[2] / 2;     // 320000
  const int N2 = 2 * N, E2 = 2 * E;
  const int NB = (N2 + 255) / 256;

  char* p = (char*)d_ws;
  unsigned short* x_bf = (unsigned short*)p; p += (size_t)N2 * 128 * 2;
  unsigned short* aggx = (unsigned short*)p; p += (size_t)N2 * 128 * 2;
  unsigned short* buf0 = (unsigned short*)p; p += (size_t)N2 * HD * 2;
  unsigned short* buf1 = (unsigned short*)p; p += (size_t)N2 * HD * 2;
  unsigned short* Wt0  = (unsigned short*)p; p += (size_t)128 * HD * 2;
  unsigned short* Wt1  = (unsigned short*)p; p += (size_t)HD * HD * 2;
  unsigned short* Wt2  = (unsigned short*)p; p += (size_t)HD * HD * 2;
  float* dinv   = (float*)p; p += (size_t)N2 * 4;
  float* scores = (float*)p; p += (size_t)GB * 512 * 4;
  float* h1     = (float*)p; p += (size_t)GB * 256 * 4;
  int2* csr    = (int2*)p; p += (size_t)E2 * 8;
  int* deg     = (int*)p; p += (size_t)N2 * 4;
  int* row_ptr = (int*)p; p += (size_t)(N2 + 1) * 4;
  int* cursor  = (int*)p; p += (size_t)N2 * 4;
  int* partial = (int*)p; p += 256 * 4;

  // prep
  k_prep3<<<(163840 + 255) / 256, 256, 0, stream>>>(W0, W1, W2, Wt0, Wt1, Wt2);
  int n4 = N * 128 / 4;
  k_cvt2<<<(2 * n4 + 255) / 256, 256, 0, stream>>>(
      (const float4*)x1, (const float4*)x2, (ushort4*)x_bf, n4);
  k_zero<<<(GB * 512 + N2 + 255) / 256, 256, 0, stream>>>(scores, deg, GB * 512, N2);

  // merged CSR
  k_deg2<<<(2 * E + 255) / 256, 256, 0, stream>>>(ei1 + E, ei2 + E, deg, E, N);
  k_scan_a<<<NB, 256, 0, stream>>>(deg, partial, N2);
  k_scan_b<<<1, 256, 0, stream>>>(partial, NB, row_ptr, N2, E2);
  k_scan_c<<<NB, 256, 0, stream>>>(deg, partial, row_ptr, dinv, cursor, N2);
  k_build2<<<(2 * E + 255) / 256, 256, 0, stream>>>(ei1, ei2, dinv, row_ptr,
                                                    cursor, csr, E, N);

  dim3 ggrid(N2 / 64, 2);
  // layer 0: aggregate x (128-dim) first, then GEMM with bias+relu
  k_gath<2, false><<<(N2 + 3) / 4, 256, 0, stream>>>(x_bf, row_ptr, csr, dinv,
                                                     nullptr, aggx, N2);
  k_gemm_bf<true><<<ggrid, 256, 0, stream>>>(aggx, Wt0, b0, buf0, 128);
  // layer 1
  k_gemm_bf<false><<<ggrid, 256, 0, stream>>>(buf0, Wt1, nullptr, buf1, HD);
  k_gath<4, true><<<(N2 + 3) / 4, 256, 0, stream>>>(buf1, row_ptr, csr, dinv,
                                                    b1, buf0, N2);
  // layer 2
  k_gemm_bf<false><<<ggrid, 256, 0, stream>>>(buf0, Wt2, nullptr, buf1, HD);
  k_gath<4, true><<<(N2 + 3) / 4, 256, 0, stream>>>(buf1, row_ptr, csr, dinv,
                                                    b2, buf0, N2);

  int waves = N2 / 32;
  k_pool4<<<(waves + 3) / 4, 256, 0, stream>>>(buf0, batch1, batch2, scores, N2, N);

  dim3 hgrid(GB, 4);
  k_head_a<<<hgrid, 256, 0, stream>>>(scores, lw0, lb0, h1);
  k_head_b<<<GB, 256, 0, stream>>>(h1, lw1, lb1, lw2, lb2, out);
}

// Round 9
// 239.187 us; speedup vs baseline: 29.4707x; 1.1428x over previous
//
#include <hip/hip_runtime.h>
#include <hip/hip_bf16.h>
#include <math.h>

#define HD 256
#define GB 128

typedef __attribute__((ext_vector_type(8))) short bf16x8;
typedef __attribute__((ext_vector_type(4))) float f32x4;
typedef __attribute__((ext_vector_type(2))) float f32x2;

__device__ __forceinline__ float bf2f(unsigned short u) {
  return __uint_as_float(((unsigned int)u) << 16);
}
__device__ __forceinline__ unsigned short f2bf(float f) {
  unsigned int u = __float_as_uint(f);
  unsigned int r = u + 0x7FFFu + ((u >> 16) & 1u);
  return (unsigned short)(r >> 16);
}

// ---------- fp8 e4m3 helpers ----------
__device__ __forceinline__ float f8dec(unsigned u) {   // decodes low byte
  unsigned s = (u >> 7) & 1u, e = (u >> 3) & 15u, m = u & 7u;
  float mag = e ? __uint_as_float(((e + 120u) << 23) | (m << 20))
                : (float)m * 0.001953125f;
  return s ? -mag : mag;
}
__device__ __forceinline__ unsigned f8enc(float x) {
#if __has_builtin(__builtin_amdgcn_cvt_pk_fp8_f32)
  return (unsigned)__builtin_amdgcn_cvt_pk_fp8_f32(x, x, 0, false) & 0xFFu;
#else
  float a = fabsf(x);
  unsigned s = x < 0.f ? 0x80u : 0u;
  if (a >= 440.f) return s | 0x7Eu;
  if (a < 0.015625f) {
    int q = (int)rintf(a * 512.f);     // 0..8 ; 8 == min normal code
    return s | (unsigned)q;
  }
  unsigned u = __float_as_uint(a);
  u += 0x7FFFFu + ((u >> 20) & 1u);
  unsigned e = (u >> 23) - 120u;
  if (e >= 16u) return s | 0x7Eu;
  return s | (e << 3) | ((u >> 20) & 7u);
#endif
}

template<int FB>
__device__ __forceinline__ void load_row_f8(const unsigned char* p, float (&f)[FB]) {
  if constexpr (FB == 4) {
    unsigned u = *(const unsigned*)p;
#if __has_builtin(__builtin_amdgcn_cvt_pk_f32_fp8)
    f32x2 lo = __builtin_amdgcn_cvt_pk_f32_fp8((int)u, false);
    f32x2 hi = __builtin_amdgcn_cvt_pk_f32_fp8((int)u, true);
    f[0] = lo[0]; f[1] = lo[1]; f[2] = hi[0]; f[3] = hi[1];
#else
    f[0] = f8dec(u); f[1] = f8dec(u >> 8); f[2] = f8dec(u >> 16); f[3] = f8dec(u >> 24);
#endif
  } else {
    unsigned u = *(const unsigned short*)p;
#if __has_builtin(__builtin_amdgcn_cvt_pk_f32_fp8)
    f32x2 lo = __builtin_amdgcn_cvt_pk_f32_fp8((int)u, false);
    f[0] = lo[0]; f[1] = lo[1];
#else
    f[0] = f8dec(u); f[1] = f8dec(u >> 8);
#endif
  }
}

// ---------- merged prep: weight pack (bf16) + x->fp8 + zero scores/deg ----------
__global__ __launch_bounds__(256) void k_prep(const float* __restrict__ W0, const float* __restrict__ W1,
                                              const float* __restrict__ W2,
                                              unsigned short* __restrict__ Wt0,
                                              unsigned short* __restrict__ Wt1,
                                              unsigned short* __restrict__ Wt2,
                                              const float4* __restrict__ x1, const float4* __restrict__ x2,
                                              unsigned* __restrict__ x8, int n4,
                                              float* __restrict__ scores, int* __restrict__ deg, int nd) {
  int i = blockIdx.x * blockDim.x + threadIdx.x;
  if (i < 163840) {
    const float* W; unsigned short* Wt; int j;
    if (i < 32768)      { W = W0; Wt = Wt0; j = i; }
    else if (i < 98304) { W = W1; Wt = Wt1; j = i - 32768; }
    else                { W = W2; Wt = Wt2; j = i - 98304; }
    int k = j >> 8, c = j & 255;
    Wt[(((size_t)(k >> 3) * HD) + c) * 8 + (k & 7)] = f2bf(W[(size_t)k * HD + c]);
    return;
  }
  int j = i - 163840;
  if (j < 2 * n4) {
    float4 v = (j < n4) ? x1[j] : x2[j - n4];
    x8[j] = f8enc(v.x) | (f8enc(v.y) << 8) | (f8enc(v.z) << 16) | (f8enc(v.w) << 24);
    return;
  }
  j -= 2 * n4;
  if (j < GB * 512) { scores[j] = 0.f; return; }
  j -= GB * 512;
  if (j < nd) deg[j] = 0;
}

__global__ void k_deg2(const int* __restrict__ dst1, const int* __restrict__ dst2,
                       int* __restrict__ deg, int e, int n0) {
  int i = blockIdx.x * blockDim.x + threadIdx.x;
  if (i >= 2 * e) return;
  int d = (i < e) ? dst1[i] : (dst2[i - e] + n0);
  atomicAdd(&deg[d], 1);
}

// ---------- 3-phase scan ----------
__global__ __launch_bounds__(256) void k_scan_a(const int* __restrict__ deg,
                                                int* __restrict__ partial, int n) {
  __shared__ int sh[256];
  int i = blockIdx.x * 256 + threadIdx.x;
  int v = (i < n) ? deg[i] : 0;
  sh[threadIdx.x] = v;
  __syncthreads();
#pragma unroll
  for (int off = 128; off; off >>= 1) {
    if (threadIdx.x < off) sh[threadIdx.x] += sh[threadIdx.x + off];
    __syncthreads();
  }
  if (threadIdx.x == 0) partial[blockIdx.x] = sh[0];
}

__global__ __launch_bounds__(256) void k_scan_b(int* __restrict__ partial, int nb,
                                                int* __restrict__ row_ptr, int n, int e_total) {
  __shared__ int sh[256];
  int t = threadIdx.x;
  int v = (t < nb) ? partial[t] : 0;
  sh[t] = v;
  __syncthreads();
#pragma unroll
  for (int off = 1; off < 256; off <<= 1) {
    int u = (t >= off) ? sh[t - off] : 0;
    __syncthreads();
    sh[t] += u;
    __syncthreads();
  }
  if (t < nb) partial[t] = sh[t] - v;
  if (t == 0) row_ptr[n] = e_total;
}

__global__ __launch_bounds__(256) void k_scan_c(const int* __restrict__ deg,
                                                const int* __restrict__ partial,
                                                int* __restrict__ row_ptr,
                                                float* __restrict__ dinv,
                                                int* __restrict__ cursor, int n) {
  __shared__ int sh[256];
  int i = blockIdx.x * 256 + threadIdx.x;
  int t = threadIdx.x;
  int v = (i < n) ? deg[i] : 0;
  sh[t] = v;
  __syncthreads();
#pragma unroll
  for (int off = 1; off < 256; off <<= 1) {
    int u = (t >= off) ? sh[t - off] : 0;
    __syncthreads();
    sh[t] += u;
    __syncthreads();
  }
  if (i < n) {
    row_ptr[i] = sh[t] - v + partial[blockIdx.x];
    dinv[i] = rsqrtf((float)(v + 1));
    cursor[i] = 0;
  }
}

__global__ void k_build2(const int* __restrict__ ei1, const int* __restrict__ ei2,
                         const float* __restrict__ dinv, const int* __restrict__ row_ptr,
                         int* __restrict__ cursor, int2* __restrict__ csr, int e, int n0) {
  int i = blockIdx.x * blockDim.x + threadIdx.x;
  if (i >= 2 * e) return;
  int s, d;
  if (i < e) { s = ei1[i];          d = ei1[i + e]; }
  else       { s = ei2[i - e] + n0; d = ei2[i] + n0; }
  int pos = atomicAdd(&cursor[d], 1);
  int idx = row_ptr[d] + pos;
  csr[idx] = make_int2(s, __float_as_int(dinv[s] * dinv[d]));
}

// ---------- MFMA bf16 GEMM: C[M,256] = A[M,K] @ W; out bf16(+bias+relu) or fp8 ----------
template<bool BR, bool F8OUT>
__global__ __launch_bounds__(256) void k_gemm_bf(const unsigned short* __restrict__ A,
                                                 const unsigned short* __restrict__ Wt,
                                                 const float* __restrict__ bias,
                                                 void* __restrict__ Cv,
                                                 int K) {
  const int w = threadIdx.x >> 6;
  const int lane = threadIdx.x & 63;
  const int bm = blockIdx.x * 64 + w * 16;
  const int bn = blockIdx.y * 128;
  const int row = bm + (lane & 15);
  const int kg0 = lane >> 4;
  f32x4 acc[8];
#pragma unroll
  for (int i = 0; i < 8; ++i) acc[i] = (f32x4){0.f, 0.f, 0.f, 0.f};

  const unsigned short* arow = A + (size_t)row * K + kg0 * 8;
  for (int k0 = 0; k0 < K; k0 += 32) {
    bf16x8 a = *(const bf16x8*)(arow + k0);
    const unsigned short* bbase =
        Wt + (((size_t)((k0 >> 3) + kg0) * HD) + bn + (lane & 15)) * 8;
#pragma unroll
    for (int nt = 0; nt < 8; ++nt) {
      bf16x8 b = *(const bf16x8*)(bbase + (size_t)nt * 16 * 8);
      acc[nt] = __builtin_amdgcn_mfma_f32_16x16x32_bf16(a, b, acc[nt], 0, 0, 0);
    }
  }
  const int crow = bm + (lane >> 4) * 4;
  const int ccol = bn + (lane & 15);
#pragma unroll
  for (int nt = 0; nt < 8; ++nt) {
    float bb = BR ? bias[ccol + nt * 16] : 0.f;
#pragma unroll
    for (int r = 0; r < 4; ++r) {
      float v = acc[nt][r];
      if (BR) v = fmaxf(v + bb, 0.f);
      size_t idx = (size_t)(crow + r) * HD + ccol + nt * 16;
      if constexpr (F8OUT) ((unsigned char*)Cv)[idx] = (unsigned char)f8enc(v);
      else                 ((unsigned short*)Cv)[idx] = f2bf(v);
    }
  }
}

// ---------- fused gather: fp8 in, bf16 out; FB fp8 elems/lane (F = FB*64 feats) ----------
template<int FB, bool BR>
__global__ __launch_bounds__(256) void k_gathf8(const unsigned char* __restrict__ y,
                                                const int* __restrict__ row_ptr,
                                                const int2* __restrict__ csr,
                                                const float* __restrict__ dinv,
                                                const float* __restrict__ bias,
                                                unsigned short* __restrict__ out, int n) {
  constexpr int F = FB * 64;
  int node = (blockIdx.x * blockDim.x + threadIdx.x) >> 6;
  int lane = threadIdx.x & 63;
  if (node >= n) return;
  float di = dinv[node];
  float c = di * di;
  float self[FB], acc0[FB], acc1[FB];
  load_row_f8<FB>(y + (size_t)node * F + lane * FB, self);
#pragma unroll
  for (int q = 0; q < FB; ++q) { acc0[q] = c * self[q]; acc1[q] = 0.f; }

  int e = row_ptr[node], end = row_ptr[node + 1];
  while (e < end) {
    int cnt = min(end - e, 64);
    int2 ew = make_int2(0, 0);
    if (lane < cnt) ew = csr[e + lane];
    int j = 0;
    for (; j + 4 <= cnt; j += 4) {
      int s0 = __shfl(ew.x, j + 0), s1 = __shfl(ew.x, j + 1);
      int s2 = __shfl(ew.x, j + 2), s3 = __shfl(ew.x, j + 3);
      float w0 = __int_as_float(__shfl(ew.y, j + 0));
      float w1 = __int_as_float(__shfl(ew.y, j + 1));
      float w2 = __int_as_float(__shfl(ew.y, j + 2));
      float w3 = __int_as_float(__shfl(ew.y, j + 3));
      float r0[FB], r1[FB], r2[FB], r3[FB];
      load_row_f8<FB>(y + (size_t)s0 * F + lane * FB, r0);
      load_row_f8<FB>(y + (size_t)s1 * F + lane * FB, r1);
      load_row_f8<FB>(y + (size_t)s2 * F + lane * FB, r2);
      load_row_f8<FB>(y + (size_t)s3 * F + lane * FB, r3);
#pragma unroll
      for (int q = 0; q < FB; ++q) {
        acc0[q] = fmaf(w0, r0[q], acc0[q]);
        acc1[q] = fmaf(w1, r1[q], acc1[q]);
        acc0[q] = fmaf(w2, r2[q], acc0[q]);
        acc1[q] = fmaf(w3, r3[q], acc1[q]);
      }
    }
    for (; j < cnt; ++j) {
      int s0 = __shfl(ew.x, j);
      float w0 = __int_as_float(__shfl(ew.y, j));
      float r0[FB];
      load_row_f8<FB>(y + (size_t)s0 * F + lane * FB, r0);
#pragma unroll
      for (int q = 0; q < FB; ++q) acc0[q] = fmaf(w0, r0[q], acc0[q]);
    }
    e += cnt;
  }
  unsigned short o[FB];
#pragma unroll
  for (int q = 0; q < FB; ++q) {
    float v = acc0[q] + acc1[q];
    if (BR) v = fmaxf(v + bias[lane * FB + q], 0.f);
    o[q] = f2bf(v);
  }
  if constexpr (FB == 4) {
    ushort4 ov; ov.x = o[0]; ov.y = o[1]; ov.z = o[2]; ov.w = o[3];
    *(ushort4*)(out + (size_t)node * F + lane * FB) = ov;
  } else {
    ushort2 ov; ov.x = o[0]; ov.y = o[1];
    *(ushort2*)(out + (size_t)node * F + lane * FB) = ov;
  }
}

// ---------- pool over merged node space (bf16 in) ----------
__global__ __launch_bounds__(256) void k_pool4(const unsigned short* __restrict__ h,
                                               const int* __restrict__ batch1,
                                               const int* __restrict__ batch2,
                                               float* __restrict__ scores,
                                               int n, int n0) {
  int wave = (blockIdx.x * blockDim.x + threadIdx.x) >> 6;
  int lane = threadIdx.x & 63;
  int beg = wave * 32;
  if (beg >= n) return;
  int end = min(beg + 32, n);
  bool g1 = beg >= n0;
  const int* bat = g1 ? batch2 : batch1;
  int boff = g1 ? n0 : 0;
  int coff = g1 ? HD : 0;
  float ax = 0.f, ay = 0.f, az = 0.f, aw = 0.f;
  int cur = bat[beg - boff];
  for (int i = beg; i < end; ++i) {
    int b = bat[i - boff];
    if (b != cur) {
      float* srow = &scores[(size_t)cur * 512 + coff + lane * 4];
      atomicAdd(&srow[0], ax); atomicAdd(&srow[1], ay);
      atomicAdd(&srow[2], az); atomicAdd(&srow[3], aw);
      ax = ay = az = aw = 0.f;
      cur = b;
    }
    ushort4 v = reinterpret_cast<const ushort4*>(h + (size_t)i * HD)[lane];
    ax += bf2f(v.x); ay += bf2f(v.y); az += bf2f(v.z); aw += bf2f(v.w);
  }
  float* srow = &scores[(size_t)cur * 512 + coff + lane * 4];
  atomicAdd(&srow[0], ax); atomicAdd(&srow[1], ay);
  atomicAdd(&srow[2], az); atomicAdd(&srow[3], aw);
}

// ---------- head layer 0 ----------
__global__ __launch_bounds__(256) void k_head_a(const float* __restrict__ scores,
                                                const float* __restrict__ lw0,
                                                const float* __restrict__ lb0,
                                                float* __restrict__ h1) {
  __shared__ float s_in[512];
  __shared__ float part[4][64];
  const int r = blockIdx.x, ct = blockIdx.y;
  const int t = threadIdx.x;
  s_in[t]       = scores[(size_t)r * 512 + t];
  s_in[t + 256] = scores[(size_t)r * 512 + t + 256];
  __syncthreads();
  const int l = t & 63, w = t >> 6;
  const int col = ct * 64 + l;
  float acc = 0.f;
  const float* wp = lw0 + (size_t)(w * 128) * 256 + col;
  const float* sp = s_in + w * 128;
#pragma unroll 8
  for (int k = 0; k < 128; ++k) acc = fmaf(sp[k], wp[(size_t)k * 256], acc);
  part[w][l] = acc;
  __syncthreads();
  if (t < 64) {
    float v = part[0][t] + part[1][t] + part[2][t] + part[3][t] + lb0[ct * 64 + t];
    h1[(size_t)r * 256 + ct * 64 + t] = fmaxf(v, 0.f);
  }
}

// ---------- head layers 1+2 ----------
__global__ __launch_bounds__(256) void k_head_b(const float* __restrict__ h1,
                                                const float* __restrict__ lw1,
                                                const float* __restrict__ lb1,
                                                const float* __restrict__ lw2,
                                                const float* __restrict__ lb2,
                                                float* __restrict__ out) {
  __shared__ float s_in[256];
  __shared__ float part[2][128];
  __shared__ float s_h2[128];
  __shared__ float red[4];
  const int r = blockIdx.x;
  const int t = threadIdx.x;
  s_in[t] = h1[(size_t)r * 256 + t];
  __syncthreads();
  const int l = t & 127, w = t >> 7;
  float acc = 0.f;
  const float* wp = lw1 + (size_t)(w * 128) * 128 + l;
  const float* sp = s_in + w * 128;
#pragma unroll 8
  for (int k = 0; k < 128; ++k) acc = fmaf(sp[k], wp[(size_t)k * 128], acc);
  part[w][l] = acc;
  __syncthreads();
  if (t < 128) s_h2[t] = fmaxf(part[0][t] + part[1][t] + lb1[t], 0.f);
  __syncthreads();
  float p = (t < 128) ? s_h2[t] * lw2[t] : 0.f;
#pragma unroll
  for (int off = 32; off; off >>= 1) p += __shfl_down(p, off);
  if ((t & 63) == 0) red[t >> 6] = p;
  __syncthreads();
  if (t == 0) {
    float z = red[0] + red[1] + red[2] + red[3] + lb2[0];
    out[r] = 1.f / (1.f + expf(-z));
  }
}

extern "C" void kernel_launch(void* const* d_in, const int* in_sizes, int n_in,
                              void* d_out, int out_size, void* d_ws, size_t ws_size,
                              hipStream_t stream) {
  const float* x1 = (const float*)d_in[0];
  const float* x2 = (const float*)d_in[1];
  const int* ei1 = (const int*)d_in[2];
  const int* ei2 = (const int*)d_in[3];
  const int* batch1 = (const int*)d_in[4];
  const int* batch2 = (const int*)d_in[5];
  const float* W0 = (const float*)d_in[6];  const float* b0 = (const float*)d_in[7];
  const float* W1 = (const float*)d_in[8];  const float* b1 = (const float*)d_in[9];
  const float* W2 = (const float*)d_in[10]; const float* b2 = (const float*)d_in[11];
  const float* lw0 = (const float*)d_in[12]; const float* lb0 = (const float*)d_in[13];
  const float* lw1 = (const float*)d_in[14]; const float* lb1 = (const float*)d_in[15];
  const float* lw2 = (const float*)d_in[16]; const float* lb2 = (const float*)d_in[17];
  float* out = (float*)d_out;

  const int N = in_sizes[0] / 128;   // 20000
  const int E = in_sizes[2] / 2;     // 320000
  const int N2 = 2 * N, E2 = 2 * E;
  const int NB = (N2 + 255) / 256;

  char* p = (char*)d_ws;
  unsigned char*  x8   = (unsigned char*)p;  p += (size_t)N2 * 128;      // fp8 input
  unsigned short* aggx = (unsigned short*)p; p += (size_t)N2 * 128 * 2;  // bf16 aggregated x
  unsigned short* h    = (unsigned short*)p; p += (size_t)N2 * HD * 2;   // bf16 activations
  unsigned char*  y    = (unsigned char*)p;  p += (size_t)N2 * HD;       // fp8 pre-activations
  unsigned short* Wt0  = (unsigned short*)p; p += (size_t)128 * HD * 2;
  unsigned short* Wt1  = (unsigned short*)p; p += (size_t)HD * HD * 2;
  unsigned short* Wt2  = (unsigned short*)p; p += (size_t)HD * HD * 2;
  float* dinv   = (float*)p; p += (size_t)N2 * 4;
  float* scores = (float*)p; p += (size_t)GB * 512 * 4;
  float* h1     = (float*)p; p += (size_t)GB * 256 * 4;
  int2* csr    = (int2*)p; p += (size_t)E2 * 8;
  int* deg     = (int*)p; p += (size_t)N2 * 4;
  int* row_ptr = (int*)p; p += (size_t)(N2 + 1) * 4;
  int* cursor  = (int*)p; p += (size_t)N2 * 4;
  int* partial = (int*)p; p += 256 * 4;

  // prep: weights pack + x->fp8 + zero scores/deg, one kernel
  int n4 = N * 128 / 4;
  int prep_total = 163840 + 2 * n4 + GB * 512 + N2;
  k_prep<<<(prep_total + 255) / 256, 256, 0, stream>>>(
      W0, W1, W2, Wt0, Wt1, Wt2,
      (const float4*)x1, (const float4*)x2, (unsigned*)x8, n4, scores, deg, N2);

  // merged CSR
  k_deg2<<<(2 * E + 255) / 256, 256, 0, stream>>>(ei1 + E, ei2 + E, deg, E, N);
  k_scan_a<<<NB, 256, 0, stream>>>(deg, partial, N2);
  k_scan_b<<<1, 256, 0, stream>>>(partial, NB, row_ptr, N2, E2);
  k_scan_c<<<NB, 256, 0, stream>>>(deg, partial, row_ptr, dinv, cursor, N2);
  k_build2<<<(2 * E + 255) / 256, 256, 0, stream>>>(ei1, ei2, dinv, row_ptr,
                                                    cursor, csr, E, N);

  dim3 ggrid(N2 / 64, 2);
  // layer 0: aggregate fp8 x (128-dim), then bf16 GEMM with bias+relu -> h (bf16)
  k_gathf8<2, false><<<(N2 + 3) / 4, 256, 0, stream>>>(x8, row_ptr, csr, dinv,
                                                       nullptr, aggx, N2);
  k_gemm_bf<true, false><<<ggrid, 256, 0, stream>>>(aggx, Wt0, b0, h, 128);
  // layer 1: GEMM -> fp8 y, gather -> bf16 h (bias+relu)
  k_gemm_bf<false, true><<<ggrid, 256, 0, stream>>>(h, Wt1, nullptr, y, HD);
  k_gathf8<4, true><<<(N2 + 3) / 4, 256, 0, stream>>>(y, row_ptr, csr, dinv,
                                                      b1, h, N2);
  // layer 2
  k_gemm_bf<false, true><<<ggrid, 256, 0, stream>>>(h, Wt2, nullptr, y, HD);
  k_gathf8<4, true><<<(N2 + 3) / 4, 256, 0, stream>>>(y, row_ptr, csr, dinv,
                                                      b2, h, N2);

  int waves = N2 / 32;
  k_pool4<<<(waves + 3) / 4, 256, 0, stream>>>(h, batch1, batch2, scores, N2, N);

  dim3 hgrid(GB, 4);
  k_head_a<<<hgrid, 256, 0, stream>>>(scores, lw0, lb0, h1);
  k_head_b<<<GB, 256, 0, stream>>>(h1, lw1, lb1, lw2, lb2, out);
}